// Round 1
// baseline (2794.803 us; speedup 1.0000x reference)
//
#include <hip/hip_runtime.h>
#include <math.h>

#define NN 100000
#define FIN 128
#define HH 64
#define CC 40
#define LL 6

// ---------------- degree / norm precompute ----------------

__global__ void init_deg(float* deg, int n) {
    int i = blockIdx.x * blockDim.x + threadIdx.x;
    if (i < n) deg[i] = 1.0f;  // self loop
}

__global__ void count_deg(const int* __restrict__ dst, float* deg, int e) {
    int i = blockIdx.x * blockDim.x + threadIdx.x;
    if (i < e) atomicAdd(&deg[dst[i]], 1.0f);
}

__global__ void rsqrt_deg(float* deg, int n) {
    int i = blockIdx.x * blockDim.x + threadIdx.x;
    if (i < n) deg[i] = rsqrtf(deg[i]);
}

// ---------------- dense matmul: out[n][j] = sum_k in[n][k] * W[k][j] ----------------
// 32 rows per block, 256 threads: thread (sub = tid>>6 in 0..3, j = tid&63),
// rows handled: base + sub + 4*r, r in 0..7. W staged in LDS.

template <int K>
__global__ __launch_bounds__(256) void matmul_nk(const float* __restrict__ in,
                                                 const float* __restrict__ W,
                                                 float* __restrict__ out, int n) {
    __shared__ float Wl[K * 64];
    for (int t = threadIdx.x; t < K * 64; t += 256) Wl[t] = W[t];
    __syncthreads();

    int j = threadIdx.x & 63;
    int sub = threadIdx.x >> 6;
    int base = blockIdx.x * 32;

    float acc[8];
#pragma unroll
    for (int r = 0; r < 8; r++) acc[r] = 0.0f;

    int rowc[8];
#pragma unroll
    for (int r = 0; r < 8; r++) {
        int row = base + sub + 4 * r;
        rowc[r] = row < n ? row : (n - 1);  // clamp for loads; store guarded
    }

    for (int k = 0; k < K; k++) {
        float wv = Wl[k * 64 + j];
#pragma unroll
        for (int r = 0; r < 8; r++) acc[r] += in[(size_t)rowc[r] * K + k] * wv;
    }

#pragma unroll
    for (int r = 0; r < 8; r++) {
        int row = base + sub + 4 * r;
        if (row < n) out[(size_t)row * 64 + j] = acc[r];
    }
}

// ---------------- aggregation ----------------

// agg[i][j] = hW[i][j] * dis[i]^2   (self-loop contribution, also inits buffer)
__global__ void agg_init(const float* __restrict__ hW, const float* __restrict__ dis,
                         float* __restrict__ agg, int n) {
    int t = blockIdx.x * blockDim.x + threadIdx.x;
    if (t < n * 64) {
        int i = t >> 6;
        float d = dis[i];
        agg[t] = hW[t] * d * d;
    }
}

// one wave (64 lanes) per edge, lane j = feature j
__global__ __launch_bounds__(256) void scatter_edges(const int* __restrict__ src,
                                                     const int* __restrict__ dst,
                                                     const float* __restrict__ dis,
                                                     const float* __restrict__ hW,
                                                     float* agg, int e) {
    long long idx = (long long)blockIdx.x * blockDim.x + threadIdx.x;
    int eid = (int)(idx >> 6);
    int j = (int)(idx & 63);
    if (eid < e) {
        int s = src[eid];
        int d = dst[eid];
        float nrm = dis[s] * dis[d];
        atomicAdd(&agg[(size_t)d * 64 + j], hW[(size_t)s * 64 + j] * nrm);
    }
}

// h = relu(agg + b); jk = (layer==0) ? h : max(jk, h)
__global__ void relu_jk(const float* __restrict__ agg, const float* __restrict__ b,
                        float* __restrict__ h, float* __restrict__ jk, int n, int layer) {
    int t = blockIdx.x * blockDim.x + threadIdx.x;
    if (t < n * 64) {
        int j = t & 63;
        float v = agg[t] + b[j];
        v = v > 0.0f ? v : 0.0f;
        h[t] = v;
        jk[t] = (layer == 0) ? v : fmaxf(jk[t], v);
    }
}

// ---------------- FC + log_softmax: one wave per row ----------------

__global__ __launch_bounds__(256) void fc_logsoftmax(const float* __restrict__ jk,
                                                     const float* __restrict__ fcw,
                                                     const float* __restrict__ fcb,
                                                     float* __restrict__ out, int n) {
    __shared__ float Wl[64 * CC];
    __shared__ float Bl[CC];
    for (int t = threadIdx.x; t < 64 * CC; t += 256) Wl[t] = fcw[t];
    if (threadIdx.x < CC) Bl[threadIdx.x] = fcb[threadIdx.x];
    __syncthreads();

    int wave = threadIdx.x >> 6;
    int lane = threadIdx.x & 63;
    int row = blockIdx.x * 4 + wave;
    if (row >= n) return;

    float acc;
    if (lane < CC) {
        float a = 0.0f;
        const float* jr = jk + (size_t)row * 64;
        for (int k = 0; k < 64; k++) a += jr[k] * Wl[k * CC + lane];
        acc = a + Bl[lane];
    } else {
        acc = -INFINITY;
    }

    float m = acc;
#pragma unroll
    for (int off = 32; off; off >>= 1) m = fmaxf(m, __shfl_xor(m, off));

    float ex = (lane < CC) ? __expf(acc - m) : 0.0f;
    float s = ex;
#pragma unroll
    for (int off = 32; off; off >>= 1) s += __shfl_xor(s, off);

    if (lane < CC) out[(size_t)row * CC + lane] = acc - m - __logf(s);
}

// ---------------- host ----------------

extern "C" void kernel_launch(void* const* d_in, const int* in_sizes, int n_in,
                              void* d_out, int out_size, void* d_ws, size_t ws_size,
                              hipStream_t stream) {
    const float* x   = (const float*)d_in[0];
    const int*   edg = (const int*)d_in[1];
    const float* W0  = (const float*)d_in[2];
    const float* Ws  = (const float*)d_in[3];
    const float* bs  = (const float*)d_in[4];
    const float* fcw = (const float*)d_in[5];
    const float* fcb = (const float*)d_in[6];
    float* out = (float*)d_out;

    int n = in_sizes[0] / FIN;  // 100000
    int e = in_sizes[1] / 2;    // 1600000
    const int* src = edg;
    const int* dst = edg + e;

    char* ws = (char*)d_ws;
    size_t off = 0;
    auto alloc = [&](size_t bytes) -> void* {
        void* p = ws + off;
        off = (off + bytes + 255) & ~(size_t)255;
        return p;
    };
    float* dis = (float*)alloc((size_t)n * 4);
    float* h   = (float*)alloc((size_t)n * 64 * 4);
    float* hW  = (float*)alloc((size_t)n * 64 * 4);
    float* agg = (float*)alloc((size_t)n * 64 * 4);
    float* jk  = (float*)alloc((size_t)n * 64 * 4);

    // degree / normalization
    init_deg<<<(n + 255) / 256, 256, 0, stream>>>(dis, n);
    count_deg<<<(e + 255) / 256, 256, 0, stream>>>(dst, dis, e);
    rsqrt_deg<<<(n + 255) / 256, 256, 0, stream>>>(dis, n);

    int nh = n * 64;
    for (int l = 0; l < LL; l++) {
        if (l == 0)
            matmul_nk<FIN><<<(n + 31) / 32, 256, 0, stream>>>(x, W0, hW, n);
        else
            matmul_nk<HH><<<(n + 31) / 32, 256, 0, stream>>>(h, Ws + (size_t)(l - 1) * HH * HH, hW, n);

        agg_init<<<(nh + 255) / 256, 256, 0, stream>>>(hW, dis, agg, n);
        scatter_edges<<<((long long)e * 64 + 255) / 256, 256, 0, stream>>>(src, dst, dis, hW, agg, e);
        relu_jk<<<(nh + 255) / 256, 256, 0, stream>>>(agg, bs + (size_t)l * HH, h, jk, n, l);
    }

    fc_logsoftmax<<<(n + 3) / 4, 256, 0, stream>>>(jk, fcw, fcb, out, n);
}

// Round 2
// 1267.696 us; speedup vs baseline: 2.2046x; 2.2046x over previous
//
#include <hip/hip_runtime.h>
#include <math.h>

#define FIN 128
#define HH 64
#define CC 40
#define LL 6
#define SCAN_CHUNK 1024

// ---------------- CSR build ----------------

__global__ void zero_i32(int* p, int n) {
    int i = blockIdx.x * blockDim.x + threadIdx.x;
    if (i < n) p[i] = 0;
}

__global__ void hist_dst(const int* __restrict__ dst, int* cnt, int e) {
    int i = blockIdx.x * blockDim.x + threadIdx.x;
    if (i < e) atomicAdd(&cnt[dst[i]], 1);
}

// dis[i] = rsqrt(deg) with deg = cnt + 1 (self loop)
__global__ void compute_dis(const int* __restrict__ cnt, float* dis, int n) {
    int i = blockIdx.x * blockDim.x + threadIdx.x;
    if (i < n) dis[i] = rsqrtf((float)cnt[i] + 1.0f);
}

__global__ __launch_bounds__(256) void scan_reduce(const int* __restrict__ cnt, int* bsum, int n) {
    __shared__ int s[256];
    int base = blockIdx.x * SCAN_CHUNK;
    int t = threadIdx.x;
    int v = 0;
#pragma unroll
    for (int u = 0; u < 4; u++) {
        int i = base + t * 4 + u;
        if (i < n) v += cnt[i];
    }
    s[t] = v; __syncthreads();
    for (int off = 128; off; off >>= 1) {
        if (t < off) s[t] += s[t + off];
        __syncthreads();
    }
    if (t == 0) bsum[blockIdx.x] = s[0];
}

// exclusive scan of bsum[0..B), B <= 256, single block
__global__ __launch_bounds__(256) void scan_top(int* bsum, int B) {
    __shared__ int s[256];
    int t = threadIdx.x;
    int v = t < B ? bsum[t] : 0;
    s[t] = v; __syncthreads();
    for (int off = 1; off < 256; off <<= 1) {
        int x = t >= off ? s[t - off] : 0;
        __syncthreads();
        s[t] += x;
        __syncthreads();
    }
    if (t < B) bsum[t] = s[t] - v;
}

__global__ __launch_bounds__(256) void scan_chunk(const int* __restrict__ cnt,
                                                  const int* __restrict__ bsum,
                                                  int* row_ptr, int* cursor, int n, int e) {
    __shared__ int s[256];
    int base = blockIdx.x * SCAN_CHUNK;
    int t = threadIdx.x;
    int c[4];
    int loc = 0;
#pragma unroll
    for (int u = 0; u < 4; u++) {
        int i = base + t * 4 + u;
        c[u] = i < n ? cnt[i] : 0;
        loc += c[u];
    }
    s[t] = loc; __syncthreads();
    for (int off = 1; off < 256; off <<= 1) {
        int x = t >= off ? s[t - off] : 0;
        __syncthreads();
        s[t] += x;
        __syncthreads();
    }
    int excl = s[t] - loc + bsum[blockIdx.x];
#pragma unroll
    for (int u = 0; u < 4; u++) {
        int i = base + t * 4 + u;
        if (i < n) { row_ptr[i] = excl; cursor[i] = excl; excl += c[u]; }
    }
    if (blockIdx.x == 0 && t == 0) row_ptr[n] = e;
}

__global__ void fill_csr(const int* __restrict__ src, const int* __restrict__ dst,
                         const float* __restrict__ dis, int* cursor,
                         int* col, float* nrm, int e) {
    int i = blockIdx.x * blockDim.x + threadIdx.x;
    if (i < e) {
        int s = src[i], d = dst[i];
        int pos = atomicAdd(&cursor[d], 1);
        col[pos] = s;
        nrm[pos] = dis[s] * dis[d];
    }
}

// ---------------- dense matmul: out[n][j] = sum_k in[n][k] * W[k][j] ----------------

template <int K>
__global__ __launch_bounds__(256) void matmul_nk(const float* __restrict__ in,
                                                 const float* __restrict__ W,
                                                 float* __restrict__ out, int n) {
    __shared__ float Wl[K * 64];
    for (int t = threadIdx.x; t < K * 64; t += 256) Wl[t] = W[t];
    __syncthreads();

    int j = threadIdx.x & 63;
    int sub = threadIdx.x >> 6;
    int base = blockIdx.x * 32;

    float acc[8];
#pragma unroll
    for (int r = 0; r < 8; r++) acc[r] = 0.0f;

    int rowc[8];
#pragma unroll
    for (int r = 0; r < 8; r++) {
        int row = base + sub + 4 * r;
        rowc[r] = row < n ? row : (n - 1);
    }

    for (int k = 0; k < K; k++) {
        float wv = Wl[k * 64 + j];
#pragma unroll
        for (int r = 0; r < 8; r++) acc[r] += in[(size_t)rowc[r] * K + k] * wv;
    }

#pragma unroll
    for (int r = 0; r < 8; r++) {
        int row = base + sub + 4 * r;
        if (row < n) out[(size_t)row * 64 + j] = acc[r];
    }
}

// ---------------- fused gather + bias + relu + JK-max ----------------
// one wave per node, lane = feature

__global__ __launch_bounds__(256) void gather_relu_jk(const int* __restrict__ row_ptr,
                                                      const int* __restrict__ col,
                                                      const float* __restrict__ nrm,
                                                      const float* __restrict__ dis,
                                                      const float* __restrict__ hW,
                                                      const float* __restrict__ b,
                                                      float* __restrict__ h,
                                                      float* __restrict__ jk,
                                                      int n, int layer) {
    int wave = threadIdx.x >> 6;
    int lane = threadIdx.x & 63;
    int i = blockIdx.x * 4 + wave;
    if (i >= n) return;

    float d = dis[i];
    float acc = hW[(size_t)i * 64 + lane] * d * d;  // self loop

    int k = row_ptr[i];
    int end = row_ptr[i + 1];
    for (; k + 1 < end; k += 2) {
        int s0 = col[k], s1 = col[k + 1];
        float n0 = nrm[k], n1 = nrm[k + 1];
        float v0 = hW[(size_t)s0 * 64 + lane];
        float v1 = hW[(size_t)s1 * 64 + lane];
        acc += v0 * n0;
        acc += v1 * n1;
    }
    if (k < end) acc += hW[(size_t)col[k] * 64 + lane] * nrm[k];

    float v = fmaxf(acc + b[lane], 0.0f);
    size_t o = (size_t)i * 64 + lane;
    h[o] = v;
    jk[o] = (layer == 0) ? v : fmaxf(jk[o], v);
}

// ---------------- FC + log_softmax: one wave per row ----------------

__global__ __launch_bounds__(256) void fc_logsoftmax(const float* __restrict__ jk,
                                                     const float* __restrict__ fcw,
                                                     const float* __restrict__ fcb,
                                                     float* __restrict__ out, int n) {
    __shared__ float Wl[64 * CC];
    __shared__ float Bl[CC];
    for (int t = threadIdx.x; t < 64 * CC; t += 256) Wl[t] = fcw[t];
    if (threadIdx.x < CC) Bl[threadIdx.x] = fcb[threadIdx.x];
    __syncthreads();

    int wave = threadIdx.x >> 6;
    int lane = threadIdx.x & 63;
    int row = blockIdx.x * 4 + wave;
    if (row >= n) return;

    float acc;
    if (lane < CC) {
        float a = 0.0f;
        const float* jr = jk + (size_t)row * 64;
        for (int kk = 0; kk < 64; kk++) a += jr[kk] * Wl[kk * CC + lane];
        acc = a + Bl[lane];
    } else {
        acc = -INFINITY;
    }

    float m = acc;
#pragma unroll
    for (int off = 32; off; off >>= 1) m = fmaxf(m, __shfl_xor(m, off));

    float ex = (lane < CC) ? __expf(acc - m) : 0.0f;
    float s = ex;
#pragma unroll
    for (int off = 32; off; off >>= 1) s += __shfl_xor(s, off);

    if (lane < CC) out[(size_t)row * CC + lane] = acc - m - __logf(s);
}

// ---------------- host ----------------

extern "C" void kernel_launch(void* const* d_in, const int* in_sizes, int n_in,
                              void* d_out, int out_size, void* d_ws, size_t ws_size,
                              hipStream_t stream) {
    const float* x   = (const float*)d_in[0];
    const int*   edg = (const int*)d_in[1];
    const float* W0  = (const float*)d_in[2];
    const float* Ws  = (const float*)d_in[3];
    const float* bs  = (const float*)d_in[4];
    const float* fcw = (const float*)d_in[5];
    const float* fcb = (const float*)d_in[6];
    float* out = (float*)d_out;

    int n = in_sizes[0] / FIN;  // 100000
    int e = in_sizes[1] / 2;    // 1600000
    const int* src = edg;
    const int* dst = edg + e;

    char* ws = (char*)d_ws;
    size_t off = 0;
    auto alloc = [&](size_t bytes) -> void* {
        void* p = ws + off;
        off = (off + bytes + 255) & ~(size_t)255;
        return p;
    };
    float* dis     = (float*)alloc((size_t)n * 4);
    float* h       = (float*)alloc((size_t)n * 64 * 4);
    float* hW      = (float*)alloc((size_t)n * 64 * 4);
    float* jk      = (float*)alloc((size_t)n * 64 * 4);
    int*   cnt     = (int*)alloc((size_t)n * 4);
    int*   row_ptr = (int*)alloc((size_t)(n + 1) * 4);
    int*   cursor  = (int*)alloc((size_t)n * 4);
    int*   col     = (int*)alloc((size_t)e * 4);
    float* nrm     = (float*)alloc((size_t)e * 4);
    int*   bsum    = (int*)alloc((size_t)256 * 4);

    int B = (n + SCAN_CHUNK - 1) / SCAN_CHUNK;  // 98 for n=100000 (<=256)

    // ---- CSR build + normalization ----
    zero_i32<<<(n + 255) / 256, 256, 0, stream>>>(cnt, n);
    hist_dst<<<(e + 255) / 256, 256, 0, stream>>>(dst, cnt, e);
    compute_dis<<<(n + 255) / 256, 256, 0, stream>>>(cnt, dis, n);
    scan_reduce<<<B, 256, 0, stream>>>(cnt, bsum, n);
    scan_top<<<1, 256, 0, stream>>>(bsum, B);
    scan_chunk<<<B, 256, 0, stream>>>(cnt, bsum, row_ptr, cursor, n, e);
    fill_csr<<<(e + 255) / 256, 256, 0, stream>>>(src, dst, dis, cursor, col, nrm, e);

    // ---- layers ----
    for (int l = 0; l < LL; l++) {
        if (l == 0)
            matmul_nk<FIN><<<(n + 31) / 32, 256, 0, stream>>>(x, W0, hW, n);
        else
            matmul_nk<HH><<<(n + 31) / 32, 256, 0, stream>>>(h, Ws + (size_t)(l - 1) * HH * HH, hW, n);

        gather_relu_jk<<<(n + 3) / 4, 256, 0, stream>>>(row_ptr, col, nrm, dis, hW,
                                                        bs + (size_t)l * HH, h, jk, n, l);
    }

    fc_logsoftmax<<<(n + 3) / 4, 256, 0, stream>>>(jk, fcw, fcb, out, n);
}

// Round 3
// 774.242 us; speedup vs baseline: 3.6097x; 1.6373x over previous
//
#include <hip/hip_runtime.h>
#include <math.h>

#define FIN 128
#define HH 64
#define CC 40
#define LL 6
#define SCAN_CHUNK 1024

typedef __attribute__((ext_vector_type(8))) short bf16x8;
typedef __attribute__((ext_vector_type(4))) float f32x4;

__device__ __forceinline__ ushort f2b(float f) {
    union { float f; unsigned u; } c; c.f = f;
    unsigned u = c.u;
    return (ushort)((u + 0x7FFFu + ((u >> 16) & 1u)) >> 16);  // RNE
}
__device__ __forceinline__ float b2f(ushort h) {
    union { float f; unsigned u; } c; c.u = ((unsigned)h) << 16;
    return c.f;
}

// ---------------- casts ----------------

__global__ void cast_f32_bf16(const float* __restrict__ in, ushort* __restrict__ out, int n4) {
    int i = blockIdx.x * blockDim.x + threadIdx.x;
    if (i < n4) {
        float4 v = ((const float4*)in)[i];
        ushort4 o;
        o.x = f2b(v.x); o.y = f2b(v.y); o.z = f2b(v.z); o.w = f2b(v.w);
        ((ushort4*)out)[i] = o;
    }
}

// ---------------- CSR build ----------------

__global__ void zero_i32(int* p, int n) {
    int i = blockIdx.x * blockDim.x + threadIdx.x;
    if (i < n) p[i] = 0;
}

__global__ void hist_dst(const int* __restrict__ dst, int* cnt, int e) {
    int i = blockIdx.x * blockDim.x + threadIdx.x;
    if (i < e) atomicAdd(&cnt[dst[i]], 1);
}

__global__ void compute_dis(const int* __restrict__ cnt, float* dis, int n) {
    int i = blockIdx.x * blockDim.x + threadIdx.x;
    if (i < n) dis[i] = rsqrtf((float)cnt[i] + 1.0f);
}

__global__ __launch_bounds__(256) void scan_reduce(const int* __restrict__ cnt, int* bsum, int n) {
    __shared__ int s[256];
    int base = blockIdx.x * SCAN_CHUNK;
    int t = threadIdx.x;
    int v = 0;
#pragma unroll
    for (int u = 0; u < 4; u++) {
        int i = base + t * 4 + u;
        if (i < n) v += cnt[i];
    }
    s[t] = v; __syncthreads();
    for (int off = 128; off; off >>= 1) {
        if (t < off) s[t] += s[t + off];
        __syncthreads();
    }
    if (t == 0) bsum[blockIdx.x] = s[0];
}

__global__ __launch_bounds__(256) void scan_top(int* bsum, int B) {
    __shared__ int s[256];
    int t = threadIdx.x;
    int v = t < B ? bsum[t] : 0;
    s[t] = v; __syncthreads();
    for (int off = 1; off < 256; off <<= 1) {
        int x = t >= off ? s[t - off] : 0;
        __syncthreads();
        s[t] += x;
        __syncthreads();
    }
    if (t < B) bsum[t] = s[t] - v;
}

__global__ __launch_bounds__(256) void scan_chunk(const int* __restrict__ cnt,
                                                  const int* __restrict__ bsum,
                                                  int* row_ptr, int* cursor, int n, int e) {
    __shared__ int s[256];
    int base = blockIdx.x * SCAN_CHUNK;
    int t = threadIdx.x;
    int c[4];
    int loc = 0;
#pragma unroll
    for (int u = 0; u < 4; u++) {
        int i = base + t * 4 + u;
        c[u] = i < n ? cnt[i] : 0;
        loc += c[u];
    }
    s[t] = loc; __syncthreads();
    for (int off = 1; off < 256; off <<= 1) {
        int x = t >= off ? s[t - off] : 0;
        __syncthreads();
        s[t] += x;
        __syncthreads();
    }
    int excl = s[t] - loc + bsum[blockIdx.x];
#pragma unroll
    for (int u = 0; u < 4; u++) {
        int i = base + t * 4 + u;
        if (i < n) { row_ptr[i] = excl; cursor[i] = excl; excl += c[u]; }
    }
    if (blockIdx.x == 0 && t == 0) row_ptr[n] = e;
}

__global__ void fill_csr(const int* __restrict__ src, const int* __restrict__ dst,
                         int* cursor, int* col, int e) {
    int i = blockIdx.x * blockDim.x + threadIdx.x;
    if (i < e) {
        int pos = atomicAdd(&cursor[dst[i]], 1);
        col[pos] = src[i];
    }
}

// ---------------- MFMA matmul: out[n][64] = in[n][K] @ W[K][64], all bf16 ----------------
// One wave per 16 rows. A: row=lane&15, k=(lane>>4)*8+e. B: col=lane&15, same k map.
// D: col=lane&15, row=(lane>>4)*4+reg  [guide m89-verified].

template <int K>
__global__ __launch_bounds__(256) void matmul_mfma(const ushort* __restrict__ A,
                                                   const ushort* __restrict__ W,
                                                   ushort* __restrict__ out, int n) {
    int wave = threadIdx.x >> 6;
    int lane = threadIdx.x & 63;
    int row0 = (blockIdx.x * 4 + wave) * 16;
    if (row0 >= n) return;

    int lm = lane & 15;
    int lg = lane >> 4;
    constexpr int KH = K / 32;

    bf16x8 bfrag[4][KH];
#pragma unroll
    for (int c = 0; c < 4; c++) {
#pragma unroll
        for (int kh = 0; kh < KH; kh++) {
            int kbase = kh * 32 + lg * 8;
            int ncol = c * 16 + lm;
            bf16x8 b;
#pragma unroll
            for (int e = 0; e < 8; e++) b[e] = (short)W[(size_t)(kbase + e) * 64 + ncol];
            bfrag[c][kh] = b;
        }
    }

    bf16x8 afrag[KH];
#pragma unroll
    for (int kh = 0; kh < KH; kh++)
        afrag[kh] = *(const bf16x8*)(A + (size_t)(row0 + lm) * K + kh * 32 + lg * 8);

    f32x4 acc[4];
#pragma unroll
    for (int c = 0; c < 4; c++) acc[c] = (f32x4){0.f, 0.f, 0.f, 0.f};

#pragma unroll
    for (int c = 0; c < 4; c++)
#pragma unroll
        for (int kh = 0; kh < KH; kh++)
            acc[c] = __builtin_amdgcn_mfma_f32_16x16x32_bf16(afrag[kh], bfrag[c][kh], acc[c], 0, 0, 0);

#pragma unroll
    for (int c = 0; c < 4; c++) {
#pragma unroll
        for (int r = 0; r < 4; r++) {
            int row = row0 + lg * 4 + r;
            out[(size_t)row * 64 + c * 16 + lm] = f2b(acc[c][r]);
        }
    }
}

// ---------------- fused gather + bias + relu + JK-max (bf16 features) ----------------
// one wave per node, lane = feature; nrm recomputed from dis (no nrm array)

__global__ __launch_bounds__(256) void gather_relu_jk(const int* __restrict__ row_ptr,
                                                      const int* __restrict__ col,
                                                      const float* __restrict__ dis,
                                                      const ushort* __restrict__ hW,
                                                      const float* __restrict__ b,
                                                      ushort* __restrict__ h,
                                                      ushort* __restrict__ jk,
                                                      int n, int layer) {
    int wave = threadIdx.x >> 6;
    int lane = threadIdx.x & 63;
    int i = blockIdx.x * 4 + wave;
    if (i >= n) return;

    float dsi = dis[i];
    float acc = b2f(hW[(size_t)i * 64 + lane]) * dsi * dsi;  // self loop

    int k = row_ptr[i];
    int end = row_ptr[i + 1];
    for (; k + 3 < end; k += 4) {
        int s0 = col[k], s1 = col[k + 1], s2 = col[k + 2], s3 = col[k + 3];
        float n0 = dis[s0] * dsi, n1 = dis[s1] * dsi;
        float n2 = dis[s2] * dsi, n3 = dis[s3] * dsi;
        float v0 = b2f(hW[(size_t)s0 * 64 + lane]);
        float v1 = b2f(hW[(size_t)s1 * 64 + lane]);
        float v2 = b2f(hW[(size_t)s2 * 64 + lane]);
        float v3 = b2f(hW[(size_t)s3 * 64 + lane]);
        acc += v0 * n0 + v1 * n1;
        acc += v2 * n2 + v3 * n3;
    }
    for (; k < end; k++) {
        int s = col[k];
        acc += b2f(hW[(size_t)s * 64 + lane]) * (dis[s] * dsi);
    }

    float v = fmaxf(acc + b[lane], 0.0f);
    ushort vb = f2b(v);
    size_t o = (size_t)i * 64 + lane;
    if (layer != LL - 1) h[o] = vb;
    // relu output >= 0, so bf16 bit pattern compares like float
    jk[o] = (layer == 0) ? vb : (jk[o] > vb ? jk[o] : vb);
}

// ---------------- FC + log_softmax: one wave per row ----------------

__global__ __launch_bounds__(256) void fc_logsoftmax(const ushort* __restrict__ jk,
                                                     const float* __restrict__ fcw,
                                                     const float* __restrict__ fcb,
                                                     float* __restrict__ out, int n) {
    __shared__ float Wl[64 * CC];
    __shared__ float Bl[CC];
    for (int t = threadIdx.x; t < 64 * CC; t += 256) Wl[t] = fcw[t];
    if (threadIdx.x < CC) Bl[threadIdx.x] = fcb[threadIdx.x];
    __syncthreads();

    int wave = threadIdx.x >> 6;
    int lane = threadIdx.x & 63;
    int row = blockIdx.x * 4 + wave;
    if (row >= n) return;

    float acc;
    if (lane < CC) {
        float a = 0.0f;
        const ushort* jr = jk + (size_t)row * 64;
        for (int kk = 0; kk < 64; kk++) a += b2f(jr[kk]) * Wl[kk * CC + lane];
        acc = a + Bl[lane];
    } else {
        acc = -INFINITY;
    }

    float m = acc;
#pragma unroll
    for (int off = 32; off; off >>= 1) m = fmaxf(m, __shfl_xor(m, off));

    float ex = (lane < CC) ? __expf(acc - m) : 0.0f;
    float s = ex;
#pragma unroll
    for (int off = 32; off; off >>= 1) s += __shfl_xor(s, off);

    if (lane < CC) out[(size_t)row * CC + lane] = acc - m - __logf(s);
}

// ---------------- host ----------------

extern "C" void kernel_launch(void* const* d_in, const int* in_sizes, int n_in,
                              void* d_out, int out_size, void* d_ws, size_t ws_size,
                              hipStream_t stream) {
    const float* x   = (const float*)d_in[0];
    const int*   edg = (const int*)d_in[1];
    const float* W0  = (const float*)d_in[2];
    const float* Ws  = (const float*)d_in[3];
    const float* bs  = (const float*)d_in[4];
    const float* fcw = (const float*)d_in[5];
    const float* fcb = (const float*)d_in[6];
    float* out = (float*)d_out;

    int n = in_sizes[0] / FIN;  // 100000
    int e = in_sizes[1] / 2;    // 1600000
    const int* src = edg;
    const int* dst = edg + e;

    char* ws = (char*)d_ws;
    size_t off = 0;
    auto alloc = [&](size_t bytes) -> void* {
        void* p = ws + off;
        off = (off + bytes + 255) & ~(size_t)255;
        return p;
    };
    ushort* x16     = (ushort*)alloc((size_t)n * FIN * 2);
    ushort* w16     = (ushort*)alloc((size_t)(FIN * 64 + (LL - 1) * 64 * 64) * 2);
    ushort* h16     = (ushort*)alloc((size_t)n * 64 * 2);
    ushort* hW16    = (ushort*)alloc((size_t)n * 64 * 2);
    ushort* jk16    = (ushort*)alloc((size_t)n * 64 * 2);
    float*  dis     = (float*)alloc((size_t)n * 4);
    int*    cnt     = (int*)alloc((size_t)n * 4);
    int*    row_ptr = (int*)alloc((size_t)(n + 1) * 4);
    int*    cursor  = (int*)alloc((size_t)n * 4);
    int*    col     = (int*)alloc((size_t)e * 4);
    int*    bsum    = (int*)alloc((size_t)256 * 4);

    int B = (n + SCAN_CHUNK - 1) / SCAN_CHUNK;

    // ---- casts ----
    int xn4 = n * FIN / 4;
    cast_f32_bf16<<<(xn4 + 255) / 256, 256, 0, stream>>>(x, x16, xn4);
    // weights: W0 (contiguous FIN*64) then Ws ((LL-1)*64*64) — inputs are contiguous
    // in setup order, but W0 and Ws are separate buffers; cast each.
    int w0n4 = FIN * 64 / 4;
    cast_f32_bf16<<<(w0n4 + 255) / 256, 256, 0, stream>>>(W0, w16, w0n4);
    int wsn4 = (LL - 1) * 64 * 64 / 4;
    cast_f32_bf16<<<(wsn4 + 255) / 256, 256, 0, stream>>>(Ws, w16 + FIN * 64, wsn4);

    // ---- CSR build + normalization ----
    zero_i32<<<(n + 255) / 256, 256, 0, stream>>>(cnt, n);
    hist_dst<<<(e + 255) / 256, 256, 0, stream>>>(dst, cnt, e);
    compute_dis<<<(n + 255) / 256, 256, 0, stream>>>(cnt, dis, n);
    scan_reduce<<<B, 256, 0, stream>>>(cnt, bsum, n);
    scan_top<<<1, 256, 0, stream>>>(bsum, B);
    scan_chunk<<<B, 256, 0, stream>>>(cnt, bsum, row_ptr, cursor, n, e);
    fill_csr<<<(e + 255) / 256, 256, 0, stream>>>(src, dst, cursor, col, e);

    // ---- layers ----
    int mblocks = ((n + 15) / 16 + 3) / 4;
    for (int l = 0; l < LL; l++) {
        if (l == 0)
            matmul_mfma<FIN><<<mblocks, 256, 0, stream>>>(x16, w16, hW16, n);
        else
            matmul_mfma<HH><<<mblocks, 256, 0, stream>>>(h16, w16 + FIN * 64 + (size_t)(l - 1) * 64 * 64,
                                                         hW16, n);

        gather_relu_jk<<<(n + 3) / 4, 256, 0, stream>>>(row_ptr, col, dis, hW16,
                                                        bs + (size_t)l * HH, h16, jk16, n, l);
    }

    fc_logsoftmax<<<(n + 3) / 4, 256, 0, stream>>>(jk16, fcw, fcb, out, n);
}

// Round 4
// 532.938 us; speedup vs baseline: 5.2441x; 1.4528x over previous
//
#include <hip/hip_runtime.h>
#include <math.h>

#define FIN 128
#define HH 64
#define CC 40
#define LL 6
#define EPB 4096   // edges per block for hist/scatter

typedef __attribute__((ext_vector_type(8))) short bf16x8;
typedef __attribute__((ext_vector_type(4))) float f32x4;

__device__ __forceinline__ ushort f2b(float f) {
    union { float f; unsigned u; } c; c.f = f;
    unsigned u = c.u;
    return (ushort)((u + 0x7FFFu + ((u >> 16) & 1u)) >> 16);  // RNE
}
__device__ __forceinline__ float b2f(ushort h) {
    union { float f; unsigned u; } c; c.u = ((unsigned)h) << 16;
    return c.f;
}

// ---------------- casts ----------------

__global__ void cast_f32_bf16(const float* __restrict__ in, ushort* __restrict__ out, int n4) {
    int i = blockIdx.x * blockDim.x + threadIdx.x;
    if (i < n4) {
        float4 v = ((const float4*)in)[i];
        ushort4 o;
        o.x = f2b(v.x); o.y = f2b(v.y); o.z = f2b(v.z); o.w = f2b(v.w);
        ((ushort4*)out)[i] = o;
    }
}

__global__ void zero_i32(int* p, int n) {
    int i = blockIdx.x * blockDim.x + threadIdx.x;
    if (i < n) p[i] = 0;
}

// ---------------- bucketed CSR build ----------------
// bucket b = dst >> 9 (512 nodes per bucket)

__global__ __launch_bounds__(256) void bucket_hist(const int* __restrict__ dst, int* bcnt, int e) {
    __shared__ int lh[256];
    int t = threadIdx.x;
    lh[t] = 0;
    __syncthreads();
    int base = blockIdx.x * EPB;
#pragma unroll
    for (int u = 0; u < 16; u++) {
        int i = base + t + u * 256;
        if (i < e) atomicAdd(&lh[dst[i] >> 9], 1);
    }
    __syncthreads();
    if (lh[t]) atomicAdd(&bcnt[t], lh[t]);
}

__global__ __launch_bounds__(256) void bucket_scan(const int* __restrict__ bcnt,
                                                   int* bbase, int* bcursor, int NB, int e) {
    __shared__ int s[256];
    int t = threadIdx.x;
    int v = (t < NB) ? bcnt[t] : 0;
    s[t] = v; __syncthreads();
    for (int off = 1; off < 256; off <<= 1) {
        int x = t >= off ? s[t - off] : 0;
        __syncthreads();
        s[t] += x;
        __syncthreads();
    }
    int excl = s[t] - v;
    if (t < NB) { bbase[t] = excl; bcursor[t] = excl; }
    if (t == 0) bbase[NB] = e;
}

__global__ __launch_bounds__(256) void bucket_scatter(const int* __restrict__ src,
                                                      const int* __restrict__ dst,
                                                      int* bcursor, int2* __restrict__ ebuf, int e) {
    __shared__ int lh[256];
    __shared__ int lbase[256];
    int t = threadIdx.x;
    int base = blockIdx.x * EPB;
    lh[t] = 0;
    __syncthreads();

    int ls[16], ld[16];
#pragma unroll
    for (int u = 0; u < 16; u++) {
        int i = base + t + u * 256;
        if (i < e) { ls[u] = src[i]; ld[u] = dst[i]; }
        else       { ls[u] = 0;      ld[u] = -1; }
    }
#pragma unroll
    for (int u = 0; u < 16; u++)
        if (ld[u] >= 0) atomicAdd(&lh[ld[u] >> 9], 1);
    __syncthreads();

    int nb = lh[t];
    if (nb > 0) lbase[t] = atomicAdd(&bcursor[t], nb);
    lh[t] = 0;
    __syncthreads();

#pragma unroll
    for (int u = 0; u < 16; u++) {
        if (ld[u] >= 0) {
            int bq = ld[u] >> 9;
            int p = atomicAdd(&lh[bq], 1);
            ebuf[lbase[bq] + p] = make_int2(ls[u], ld[u]);
        }
    }
}

// one block per bucket: per-node counts (LDS), local scan -> row_ptr + dis + cursor,
// then scatter col into the bucket's contiguous window (L2-resident).
__global__ __launch_bounds__(256) void bucket_fill(const int* __restrict__ bbase,
                                                   const int2* __restrict__ ebuf,
                                                   int* __restrict__ row_ptr,
                                                   float* __restrict__ dis,
                                                   int* __restrict__ col, int n, int e) {
    __shared__ int nc[512];
    __shared__ int cur[512];
    __shared__ int sp[256];
    int b = blockIdx.x, t = threadIdx.x;
    int node0 = b << 9;
    int estart = bbase[b], eend = bbase[b + 1];

    nc[t] = 0; nc[t + 256] = 0;
    __syncthreads();
    for (int i = estart + t; i < eend; i += 256)
        atomicAdd(&nc[ebuf[i].y - node0], 1);
    __syncthreads();

    int c0 = nc[2 * t], c1 = nc[2 * t + 1];
    int pair = c0 + c1;
    sp[t] = pair; __syncthreads();
    for (int off = 1; off < 256; off <<= 1) {
        int x = t >= off ? sp[t - off] : 0;
        __syncthreads();
        sp[t] += x;
        __syncthreads();
    }
    int excl = sp[t] - pair;
    cur[2 * t] = excl;
    cur[2 * t + 1] = excl + c0;

    int n0 = node0 + 2 * t, n1 = node0 + 2 * t + 1;
    if (n0 < n) { row_ptr[n0] = estart + excl;      dis[n0] = rsqrtf((float)c0 + 1.0f); }
    if (n1 < n) { row_ptr[n1] = estart + excl + c0; dis[n1] = rsqrtf((float)c1 + 1.0f); }
    if (b == 0 && t == 0) row_ptr[n] = e;
    __syncthreads();

    for (int i = estart + t; i < eend; i += 256) {
        int2 sd = ebuf[i];
        int p = atomicAdd(&cur[sd.y - node0], 1);
        col[estart + p] = sd.x;
    }
}

// ---------------- MFMA matmul: out[n][64] = in[n][K] @ W[K][64], all bf16 ----------------

template <int K>
__global__ __launch_bounds__(256) void matmul_mfma(const ushort* __restrict__ A,
                                                   const ushort* __restrict__ W,
                                                   ushort* __restrict__ out, int n) {
    int wave = threadIdx.x >> 6;
    int lane = threadIdx.x & 63;
    int row0 = (blockIdx.x * 4 + wave) * 16;
    if (row0 >= n) return;

    int lm = lane & 15;
    int lg = lane >> 4;
    constexpr int KH = K / 32;

    bf16x8 bfrag[4][KH];
#pragma unroll
    for (int c = 0; c < 4; c++) {
#pragma unroll
        for (int kh = 0; kh < KH; kh++) {
            int kbase = kh * 32 + lg * 8;
            int ncol = c * 16 + lm;
            bf16x8 bb;
#pragma unroll
            for (int e2 = 0; e2 < 8; e2++) bb[e2] = (short)W[(size_t)(kbase + e2) * 64 + ncol];
            bfrag[c][kh] = bb;
        }
    }

    bf16x8 afrag[KH];
#pragma unroll
    for (int kh = 0; kh < KH; kh++)
        afrag[kh] = *(const bf16x8*)(A + (size_t)(row0 + lm) * K + kh * 32 + lg * 8);

    f32x4 acc[4];
#pragma unroll
    for (int c = 0; c < 4; c++) acc[c] = (f32x4){0.f, 0.f, 0.f, 0.f};

#pragma unroll
    for (int c = 0; c < 4; c++)
#pragma unroll
        for (int kh = 0; kh < KH; kh++)
            acc[c] = __builtin_amdgcn_mfma_f32_16x16x32_bf16(afrag[kh], bfrag[c][kh], acc[c], 0, 0, 0);

#pragma unroll
    for (int c = 0; c < 4; c++) {
#pragma unroll
        for (int r = 0; r < 4; r++) {
            int row = row0 + lg * 4 + r;
            out[(size_t)row * 64 + c * 16 + lm] = f2b(acc[c][r]);
        }
    }
}

// ---------------- fused gather + bias + relu + JK-max (bf16 features) ----------------
// 4 nodes per wave (16 lanes each), lane handles 4 features via ushort4 loads.

__global__ __launch_bounds__(256) void gather_relu_jk(const int* __restrict__ row_ptr,
                                                      const int* __restrict__ col,
                                                      const float* __restrict__ dis,
                                                      const ushort* __restrict__ hW,
                                                      const float* __restrict__ b,
                                                      ushort* __restrict__ h,
                                                      ushort* __restrict__ jk,
                                                      int n, int layer) {
    int wave = threadIdx.x >> 6;
    int lane = threadIdx.x & 63;
    int sub = lane >> 4;
    int fl = (lane & 15) * 4;
    int i = (blockIdx.x * 4 + wave) * 4 + sub;
    if (i >= n) return;

    float dsi = dis[i];
    ushort4 sv = *(const ushort4*)(hW + (size_t)i * 64 + fl);
    float d2 = dsi * dsi;
    float a0 = b2f(sv.x) * d2, a1 = b2f(sv.y) * d2, a2 = b2f(sv.z) * d2, a3 = b2f(sv.w) * d2;

    int k = row_ptr[i];
    int end = row_ptr[i + 1];
    for (; k + 1 < end; k += 2) {
        int s0 = col[k], s1 = col[k + 1];
        float q0 = dis[s0] * dsi, q1 = dis[s1] * dsi;
        ushort4 v0 = *(const ushort4*)(hW + (size_t)s0 * 64 + fl);
        ushort4 v1 = *(const ushort4*)(hW + (size_t)s1 * 64 + fl);
        a0 += b2f(v0.x) * q0 + b2f(v1.x) * q1;
        a1 += b2f(v0.y) * q0 + b2f(v1.y) * q1;
        a2 += b2f(v0.z) * q0 + b2f(v1.z) * q1;
        a3 += b2f(v0.w) * q0 + b2f(v1.w) * q1;
    }
    if (k < end) {
        int s0 = col[k];
        float q0 = dis[s0] * dsi;
        ushort4 v0 = *(const ushort4*)(hW + (size_t)s0 * 64 + fl);
        a0 += b2f(v0.x) * q0; a1 += b2f(v0.y) * q0;
        a2 += b2f(v0.z) * q0; a3 += b2f(v0.w) * q0;
    }

    float4 bb = *(const float4*)(b + fl);
    ushort4 hv;
    hv.x = f2b(fmaxf(a0 + bb.x, 0.0f));
    hv.y = f2b(fmaxf(a1 + bb.y, 0.0f));
    hv.z = f2b(fmaxf(a2 + bb.z, 0.0f));
    hv.w = f2b(fmaxf(a3 + bb.w, 0.0f));

    size_t o = (size_t)i * 64 + fl;
    if (layer != LL - 1) *(ushort4*)(h + o) = hv;

    if (layer == 0) {
        *(ushort4*)(jk + o) = hv;
    } else {
        ushort4 jv = *(const ushort4*)(jk + o);
        // relu outputs >= 0 -> bf16 bits compare like floats
        jv.x = jv.x > hv.x ? jv.x : hv.x;
        jv.y = jv.y > hv.y ? jv.y : hv.y;
        jv.z = jv.z > hv.z ? jv.z : hv.z;
        jv.w = jv.w > hv.w ? jv.w : hv.w;
        *(ushort4*)(jk + o) = jv;
    }
}

// ---------------- FC + log_softmax: one wave per row ----------------

__global__ __launch_bounds__(256) void fc_logsoftmax(const ushort* __restrict__ jk,
                                                     const float* __restrict__ fcw,
                                                     const float* __restrict__ fcb,
                                                     float* __restrict__ out, int n) {
    __shared__ float Wl[64 * CC];
    __shared__ float Bl[CC];
    for (int t = threadIdx.x; t < 64 * CC; t += 256) Wl[t] = fcw[t];
    if (threadIdx.x < CC) Bl[threadIdx.x] = fcb[threadIdx.x];
    __syncthreads();

    int wave = threadIdx.x >> 6;
    int lane = threadIdx.x & 63;
    int row = blockIdx.x * 4 + wave;
    if (row >= n) return;

    float acc;
    if (lane < CC) {
        float a = 0.0f;
        const ushort* jr = jk + (size_t)row * 64;
        for (int kk = 0; kk < 64; kk++) a += b2f(jr[kk]) * Wl[kk * CC + lane];
        acc = a + Bl[lane];
    } else {
        acc = -INFINITY;
    }

    float m = acc;
#pragma unroll
    for (int off = 32; off; off >>= 1) m = fmaxf(m, __shfl_xor(m, off));

    float ex = (lane < CC) ? __expf(acc - m) : 0.0f;
    float s = ex;
#pragma unroll
    for (int off = 32; off; off >>= 1) s += __shfl_xor(s, off);

    if (lane < CC) out[(size_t)row * CC + lane] = acc - m - __logf(s);
}

// ---------------- host ----------------

extern "C" void kernel_launch(void* const* d_in, const int* in_sizes, int n_in,
                              void* d_out, int out_size, void* d_ws, size_t ws_size,
                              hipStream_t stream) {
    const float* x   = (const float*)d_in[0];
    const int*   edg = (const int*)d_in[1];
    const float* W0  = (const float*)d_in[2];
    const float* Ws  = (const float*)d_in[3];
    const float* bs  = (const float*)d_in[4];
    const float* fcw = (const float*)d_in[5];
    const float* fcb = (const float*)d_in[6];
    float* out = (float*)d_out;

    int n = in_sizes[0] / FIN;  // 100000
    int e = in_sizes[1] / 2;    // 1600000
    const int* src = edg;
    const int* dst = edg + e;

    char* ws = (char*)d_ws;
    size_t off = 0;
    auto alloc = [&](size_t bytes) -> void* {
        void* p = ws + off;
        off = (off + bytes + 255) & ~(size_t)255;
        return p;
    };
    ushort* x16     = (ushort*)alloc((size_t)n * FIN * 2);
    ushort* w16     = (ushort*)alloc((size_t)(FIN * 64 + (LL - 1) * 64 * 64) * 2);
    ushort* h16     = (ushort*)alloc((size_t)n * 64 * 2);
    ushort* hW16    = (ushort*)alloc((size_t)n * 64 * 2);
    ushort* jk16    = (ushort*)alloc((size_t)n * 64 * 2);
    float*  dis     = (float*)alloc((size_t)n * 4);
    int*    row_ptr = (int*)alloc((size_t)(n + 1) * 4);
    int*    col     = (int*)alloc((size_t)e * 4);
    int2*   ebuf    = (int2*)alloc((size_t)e * 8);
    int*    bcnt    = (int*)alloc(256 * 4);
    int*    bbase   = (int*)alloc(257 * 4);
    int*    bcursor = (int*)alloc(256 * 4);

    int NB = (n + 511) >> 9;          // 196 buckets
    int EB = (e + EPB - 1) / EPB;     // 391 edge blocks

    // ---- casts ----
    int xn4 = n * FIN / 4;
    cast_f32_bf16<<<(xn4 + 255) / 256, 256, 0, stream>>>(x, x16, xn4);
    int w0n4 = FIN * 64 / 4;
    cast_f32_bf16<<<(w0n4 + 255) / 256, 256, 0, stream>>>(W0, w16, w0n4);
    int wsn4 = (LL - 1) * 64 * 64 / 4;
    cast_f32_bf16<<<(wsn4 + 255) / 256, 256, 0, stream>>>(Ws, w16 + FIN * 64, wsn4);

    // ---- bucketed CSR build ----
    zero_i32<<<1, 256, 0, stream>>>(bcnt, 256);
    bucket_hist<<<EB, 256, 0, stream>>>(dst, bcnt, e);
    bucket_scan<<<1, 256, 0, stream>>>(bcnt, bbase, bcursor, NB, e);
    bucket_scatter<<<EB, 256, 0, stream>>>(src, dst, bcursor, ebuf, e);
    bucket_fill<<<NB, 256, 0, stream>>>(bbase, ebuf, row_ptr, dis, col, n, e);

    // ---- layers ----
    int mblocks = ((n + 15) / 16 + 3) / 4;
    int gblocks = (n + 15) / 16;
    for (int l = 0; l < LL; l++) {
        if (l == 0)
            matmul_mfma<FIN><<<mblocks, 256, 0, stream>>>(x16, w16, hW16, n);
        else
            matmul_mfma<HH><<<mblocks, 256, 0, stream>>>(h16, w16 + FIN * 64 + (size_t)(l - 1) * 64 * 64,
                                                         hW16, n);

        gather_relu_jk<<<gblocks, 256, 0, stream>>>(row_ptr, col, dis, hW16,
                                                    bs + (size_t)l * HH, h16, jk16, n, l);
    }

    fc_logsoftmax<<<(n + 3) / 4, 256, 0, stream>>>(jk16, fcw, fcb, out, n);
}

// Round 5
// 418.155 us; speedup vs baseline: 6.6837x; 1.2745x over previous
//
#include <hip/hip_runtime.h>
#include <math.h>

#define FIN 128
#define HH 64
#define CC 40
#define LL 6
#define EPB 4096   // edges per block for hist/scatter

typedef __attribute__((ext_vector_type(8))) short bf16x8;
typedef __attribute__((ext_vector_type(4))) float f32x4;

__device__ __forceinline__ ushort f2b(float f) {
    union { float f; unsigned u; } c; c.f = f;
    unsigned u = c.u;
    return (ushort)((u + 0x7FFFu + ((u >> 16) & 1u)) >> 16);  // RNE
}
__device__ __forceinline__ float b2f(ushort h) {
    union { float f; unsigned u; } c; c.u = ((unsigned)h) << 16;
    return c.f;
}

// ---------------- casts ----------------

__global__ void cast_f32_bf16(const float* __restrict__ in, ushort* __restrict__ out, int n4) {
    int i = blockIdx.x * blockDim.x + threadIdx.x;
    if (i < n4) {
        float4 v = ((const float4*)in)[i];
        ushort4 o;
        o.x = f2b(v.x); o.y = f2b(v.y); o.z = f2b(v.z); o.w = f2b(v.w);
        ((ushort4*)out)[i] = o;
    }
}

// fcw [64][40] f32 -> [64][48] bf16 (pad cols 40..47 with 0)
__global__ void cast_fcw48(const float* __restrict__ fcw, ushort* __restrict__ out) {
    int i = blockIdx.x * blockDim.x + threadIdx.x;  // 64*48
    if (i < 64 * 48) {
        int k = i / 48, c = i % 48;
        out[i] = (c < CC) ? f2b(fcw[k * CC + c]) : (ushort)0;
    }
}

__global__ void zero_i32(int* p, int n) {
    int i = blockIdx.x * blockDim.x + threadIdx.x;
    if (i < n) p[i] = 0;
}

// ---------------- bucketed CSR build ----------------
// bucket b = dst >> 9 (512 nodes per bucket)

__global__ __launch_bounds__(256) void bucket_hist(const int* __restrict__ dst, int* bcnt, int e) {
    __shared__ int lh[256];
    int t = threadIdx.x;
    lh[t] = 0;
    __syncthreads();
    int base = blockIdx.x * EPB;
#pragma unroll
    for (int u = 0; u < 16; u++) {
        int i = base + t + u * 256;
        if (i < e) atomicAdd(&lh[dst[i] >> 9], 1);
    }
    __syncthreads();
    if (lh[t]) atomicAdd(&bcnt[t], lh[t]);
}

__global__ __launch_bounds__(256) void bucket_scan(const int* __restrict__ bcnt,
                                                   int* bbase, int* bcursor, int NB, int e) {
    __shared__ int s[256];
    int t = threadIdx.x;
    int v = (t < NB) ? bcnt[t] : 0;
    s[t] = v; __syncthreads();
    for (int off = 1; off < 256; off <<= 1) {
        int x = t >= off ? s[t - off] : 0;
        __syncthreads();
        s[t] += x;
        __syncthreads();
    }
    int excl = s[t] - v;
    if (t < NB) { bbase[t] = excl; bcursor[t] = excl; }
    if (t == 0) bbase[NB] = e;
}

// ebuf entry: (src << 9) | (dst & 511)   [src < 2^17, 26 bits total]
__global__ __launch_bounds__(256) void bucket_scatter(const int* __restrict__ src,
                                                      const int* __restrict__ dst,
                                                      int* bcursor, unsigned* __restrict__ ebuf, int e) {
    __shared__ int lh[256];
    __shared__ int lbase[256];
    int t = threadIdx.x;
    int base = blockIdx.x * EPB;
    lh[t] = 0;
    __syncthreads();

    int ls[16], ld[16];
#pragma unroll
    for (int u = 0; u < 16; u++) {
        int i = base + t + u * 256;
        if (i < e) { ls[u] = src[i]; ld[u] = dst[i]; }
        else       { ls[u] = 0;      ld[u] = -1; }
    }
#pragma unroll
    for (int u = 0; u < 16; u++)
        if (ld[u] >= 0) atomicAdd(&lh[ld[u] >> 9], 1);
    __syncthreads();

    int nb = lh[t];
    if (nb > 0) lbase[t] = atomicAdd(&bcursor[t], nb);
    lh[t] = 0;
    __syncthreads();

#pragma unroll
    for (int u = 0; u < 16; u++) {
        if (ld[u] >= 0) {
            int bq = ld[u] >> 9;
            int p = atomicAdd(&lh[bq], 1);
            ebuf[lbase[bq] + p] = ((unsigned)ls[u] << 9) | (unsigned)(ld[u] & 511);
        }
    }
}

__global__ __launch_bounds__(256) void bucket_fill(const int* __restrict__ bbase,
                                                   const unsigned* __restrict__ ebuf,
                                                   int* __restrict__ row_ptr,
                                                   float* __restrict__ dis,
                                                   int* __restrict__ col, int n, int e) {
    __shared__ int nc[512];
    __shared__ int cur[512];
    __shared__ int sp[256];
    int b = blockIdx.x, t = threadIdx.x;
    int node0 = b << 9;
    int estart = bbase[b], eend = bbase[b + 1];

    nc[t] = 0; nc[t + 256] = 0;
    __syncthreads();
    for (int i = estart + t; i < eend; i += 256)
        atomicAdd(&nc[ebuf[i] & 511u], 1);
    __syncthreads();

    int c0 = nc[2 * t], c1 = nc[2 * t + 1];
    int pair = c0 + c1;
    sp[t] = pair; __syncthreads();
    for (int off = 1; off < 256; off <<= 1) {
        int x = t >= off ? sp[t - off] : 0;
        __syncthreads();
        sp[t] += x;
        __syncthreads();
    }
    int excl = sp[t] - pair;
    cur[2 * t] = excl;
    cur[2 * t + 1] = excl + c0;

    int n0 = node0 + 2 * t, n1 = node0 + 2 * t + 1;
    if (n0 < n) { row_ptr[n0] = estart + excl;      dis[n0] = rsqrtf((float)c0 + 1.0f); }
    if (n1 < n) { row_ptr[n1] = estart + excl + c0; dis[n1] = rsqrtf((float)c1 + 1.0f); }
    if (b == 0 && t == 0) row_ptr[n] = e;
    __syncthreads();

    for (int i = estart + t; i < eend; i += 256) {
        unsigned v = ebuf[i];
        int p = atomicAdd(&cur[v & 511u], 1);
        col[estart + p] = (int)(v >> 9);
    }
}

// ---------------- MFMA matmul: g[n][64] = (in[n][K] @ W[K][64]) * dis[row], bf16 ----------------
// Wave handles 64 rows (4 row-tiles) against one B-frag set (W amortized 4x).

template <int K>
__global__ __launch_bounds__(256) void matmul_mfma(const ushort* __restrict__ A,
                                                   const ushort* __restrict__ W,
                                                   const float* __restrict__ dis,
                                                   ushort* __restrict__ out, int n) {
    int wave = threadIdx.x >> 6;
    int lane = threadIdx.x & 63;
    int row0 = (blockIdx.x * 4 + wave) * 64;
    if (row0 >= n) return;

    int lm = lane & 15;
    int lg = lane >> 4;
    constexpr int KH = K / 32;

    bf16x8 bfrag[4][KH];
#pragma unroll
    for (int c = 0; c < 4; c++) {
#pragma unroll
        for (int kh = 0; kh < KH; kh++) {
            int kbase = kh * 32 + lg * 8;
            int ncol = c * 16 + lm;
            bf16x8 bb;
#pragma unroll
            for (int e2 = 0; e2 < 8; e2++) bb[e2] = (short)W[(size_t)(kbase + e2) * 64 + ncol];
            bfrag[c][kh] = bb;
        }
    }

    for (int rt = 0; rt < 4; rt++) {
        int r0 = row0 + rt * 16;
        if (r0 >= n) break;

        int arow = r0 + lm;
        if (arow >= n) arow = n - 1;
        bf16x8 afrag[KH];
#pragma unroll
        for (int kh = 0; kh < KH; kh++)
            afrag[kh] = *(const bf16x8*)(A + (size_t)arow * K + kh * 32 + lg * 8);

        f32x4 acc[4];
#pragma unroll
        for (int c = 0; c < 4; c++) acc[c] = (f32x4){0.f, 0.f, 0.f, 0.f};

#pragma unroll
        for (int c = 0; c < 4; c++)
#pragma unroll
            for (int kh = 0; kh < KH; kh++)
                acc[c] = __builtin_amdgcn_mfma_f32_16x16x32_bf16(afrag[kh], bfrag[c][kh], acc[c], 0, 0, 0);

        float dsr[4];
#pragma unroll
        for (int r = 0; r < 4; r++) {
            int row = r0 + lg * 4 + r;
            dsr[r] = (row < n) ? dis[row] : 0.0f;
        }
#pragma unroll
        for (int c = 0; c < 4; c++) {
#pragma unroll
            for (int r = 0; r < 4; r++) {
                int row = r0 + lg * 4 + r;
                if (row < n) out[(size_t)row * 64 + c * 16 + lm] = f2b(acc[c][r] * dsr[r]);
            }
        }
    }
}

// ---------------- fused gather + bias + relu + JK-max ----------------
// g rows are pre-scaled by dis[src]; agg = dsi * (sum g[cols] + g[i]).
// 4 nodes per wave (16 lanes each), lane handles 4 features via ushort4 loads.

__global__ __launch_bounds__(256) void gather_relu_jk(const int* __restrict__ row_ptr,
                                                      const int* __restrict__ col,
                                                      const float* __restrict__ dis,
                                                      const ushort* __restrict__ g,
                                                      const float* __restrict__ b,
                                                      ushort* __restrict__ h,
                                                      ushort* __restrict__ jk,
                                                      int n, int layer) {
    int wave = threadIdx.x >> 6;
    int lane = threadIdx.x & 63;
    int sub = lane >> 4;
    int fl = (lane & 15) * 4;
    int i = (blockIdx.x * 4 + wave) * 4 + sub;
    if (i >= n) return;

    float dsi = dis[i];
    ushort4 sv = *(const ushort4*)(g + (size_t)i * 64 + fl);
    float a0 = b2f(sv.x), a1 = b2f(sv.y), a2 = b2f(sv.z), a3 = b2f(sv.w);

    int k = row_ptr[i];
    int end = row_ptr[i + 1];
    for (; k + 3 < end; k += 4) {
        int s0 = col[k], s1 = col[k + 1], s2 = col[k + 2], s3 = col[k + 3];
        ushort4 v0 = *(const ushort4*)(g + (size_t)s0 * 64 + fl);
        ushort4 v1 = *(const ushort4*)(g + (size_t)s1 * 64 + fl);
        ushort4 v2 = *(const ushort4*)(g + (size_t)s2 * 64 + fl);
        ushort4 v3 = *(const ushort4*)(g + (size_t)s3 * 64 + fl);
        a0 += (b2f(v0.x) + b2f(v1.x)) + (b2f(v2.x) + b2f(v3.x));
        a1 += (b2f(v0.y) + b2f(v1.y)) + (b2f(v2.y) + b2f(v3.y));
        a2 += (b2f(v0.z) + b2f(v1.z)) + (b2f(v2.z) + b2f(v3.z));
        a3 += (b2f(v0.w) + b2f(v1.w)) + (b2f(v2.w) + b2f(v3.w));
    }
    for (; k < end; k++) {
        int s0 = col[k];
        ushort4 v0 = *(const ushort4*)(g + (size_t)s0 * 64 + fl);
        a0 += b2f(v0.x); a1 += b2f(v0.y); a2 += b2f(v0.z); a3 += b2f(v0.w);
    }

    float4 bb = *(const float4*)(b + fl);
    ushort4 hv;
    hv.x = f2b(fmaxf(a0 * dsi + bb.x, 0.0f));
    hv.y = f2b(fmaxf(a1 * dsi + bb.y, 0.0f));
    hv.z = f2b(fmaxf(a2 * dsi + bb.z, 0.0f));
    hv.w = f2b(fmaxf(a3 * dsi + bb.w, 0.0f));

    size_t o = (size_t)i * 64 + fl;
    if (layer != LL - 1) *(ushort4*)(h + o) = hv;

    if (layer == 0) {
        *(ushort4*)(jk + o) = hv;
    } else {
        ushort4 jv = *(const ushort4*)(jk + o);
        jv.x = jv.x > hv.x ? jv.x : hv.x;
        jv.y = jv.y > hv.y ? jv.y : hv.y;
        jv.z = jv.z > hv.z ? jv.z : hv.z;
        jv.w = jv.w > hv.w ? jv.w : hv.w;
        *(ushort4*)(jk + o) = jv;
    }
}

// ---------------- MFMA FC + log_softmax ----------------
// out[n][40] = jk[n][64] @ fcw48[64][48] (cols 40..47 padded 0), log_softmax per row.
// Wave = 16 rows; 3 col tiles x 2 k-halves = 6 MFMAs; row-reduce via shfl_xor over 16 lanes.

__global__ __launch_bounds__(256) void fc_logsoftmax_mfma(const ushort* __restrict__ jk,
                                                          const ushort* __restrict__ fcw48,
                                                          const float* __restrict__ fcb,
                                                          float* __restrict__ out, int n) {
    int wave = threadIdx.x >> 6;
    int lane = threadIdx.x & 63;
    int row0 = (blockIdx.x * 4 + wave) * 16;
    if (row0 >= n) return;

    int lm = lane & 15;
    int lg = lane >> 4;

    bf16x8 bfrag[3][2];
#pragma unroll
    for (int c = 0; c < 3; c++) {
#pragma unroll
        for (int kh = 0; kh < 2; kh++) {
            int kbase = kh * 32 + lg * 8;
            bf16x8 bb;
#pragma unroll
            for (int e2 = 0; e2 < 8; e2++) bb[e2] = (short)fcw48[(size_t)(kbase + e2) * 48 + c * 16 + lm];
            bfrag[c][kh] = bb;
        }
    }

    int arow = row0 + lm;
    if (arow >= n) arow = n - 1;
    bf16x8 afrag[2];
#pragma unroll
    for (int kh = 0; kh < 2; kh++)
        afrag[kh] = *(const bf16x8*)(jk + (size_t)arow * 64 + kh * 32 + lg * 8);

    f32x4 acc[3];
#pragma unroll
    for (int c = 0; c < 3; c++) acc[c] = (f32x4){0.f, 0.f, 0.f, 0.f};
#pragma unroll
    for (int c = 0; c < 3; c++)
#pragma unroll
        for (int kh = 0; kh < 2; kh++)
            acc[c] = __builtin_amdgcn_mfma_f32_16x16x32_bf16(afrag[kh], bfrag[c][kh], acc[c], 0, 0, 0);

    // logits + bias; mask padded cols
    bool valid[3];
    float bc[3];
#pragma unroll
    for (int c = 0; c < 3; c++) {
        int colp = c * 16 + lm;
        valid[c] = colp < CC;
        bc[c] = valid[c] ? fcb[colp] : 0.0f;
    }

#pragma unroll
    for (int r = 0; r < 4; r++) {
        float l0 = acc[0][r] + bc[0];
        float l1 = acc[1][r] + bc[1];
        float l2 = valid[2] ? (acc[2][r] + bc[2]) : -INFINITY;

        float m = fmaxf(fmaxf(l0, l1), l2);
#pragma unroll
        for (int off = 8; off; off >>= 1) m = fmaxf(m, __shfl_xor(m, off));

        float s = __expf(l0 - m) + __expf(l1 - m) + (valid[2] ? __expf(l2 - m) : 0.0f);
#pragma unroll
        for (int off = 8; off; off >>= 1) s += __shfl_xor(s, off);

        float lse = m + __logf(s);
        int row = row0 + lg * 4 + r;
        if (row < n) {
            float* orow = out + (size_t)row * CC;
            orow[lm] = l0 - lse;
            orow[16 + lm] = l1 - lse;
            if (valid[2]) orow[32 + lm] = l2 - lse;
        }
    }
}

// ---------------- host ----------------

extern "C" void kernel_launch(void* const* d_in, const int* in_sizes, int n_in,
                              void* d_out, int out_size, void* d_ws, size_t ws_size,
                              hipStream_t stream) {
    const float* x   = (const float*)d_in[0];
    const int*   edg = (const int*)d_in[1];
    const float* W0  = (const float*)d_in[2];
    const float* Ws  = (const float*)d_in[3];
    const float* bs  = (const float*)d_in[4];
    const float* fcw = (const float*)d_in[5];
    const float* fcb = (const float*)d_in[6];
    float* out = (float*)d_out;

    int n = in_sizes[0] / FIN;  // 100000
    int e = in_sizes[1] / 2;    // 1600000
    const int* src = edg;
    const int* dst = edg + e;

    char* ws = (char*)d_ws;
    size_t off = 0;
    auto alloc = [&](size_t bytes) -> void* {
        void* p = ws + off;
        off = (off + bytes + 255) & ~(size_t)255;
        return p;
    };
    ushort*   x16     = (ushort*)alloc((size_t)n * FIN * 2);
    ushort*   w16     = (ushort*)alloc((size_t)(FIN * 64 + (LL - 1) * 64 * 64) * 2);
    ushort*   fcw48   = (ushort*)alloc((size_t)64 * 48 * 2);
    ushort*   h16     = (ushort*)alloc((size_t)n * 64 * 2);
    ushort*   g16     = (ushort*)alloc((size_t)n * 64 * 2);
    ushort*   jk16    = (ushort*)alloc((size_t)n * 64 * 2);
    float*    dis     = (float*)alloc((size_t)n * 4);
    int*      row_ptr = (int*)alloc((size_t)(n + 1) * 4);
    int*      col     = (int*)alloc((size_t)e * 4);
    unsigned* ebuf    = (unsigned*)alloc((size_t)e * 4);
    int*      bcnt    = (int*)alloc(256 * 4);
    int*      bbase   = (int*)alloc(257 * 4);
    int*      bcursor = (int*)alloc(256 * 4);

    int NB = (n + 511) >> 9;          // 196 buckets
    int EB = (e + EPB - 1) / EPB;     // 391 edge blocks

    // ---- casts ----
    int xn4 = n * FIN / 4;
    cast_f32_bf16<<<(xn4 + 255) / 256, 256, 0, stream>>>(x, x16, xn4);
    int w0n4 = FIN * 64 / 4;
    cast_f32_bf16<<<(w0n4 + 255) / 256, 256, 0, stream>>>(W0, w16, w0n4);
    int wsn4 = (LL - 1) * 64 * 64 / 4;
    cast_f32_bf16<<<(wsn4 + 255) / 256, 256, 0, stream>>>(Ws, w16 + FIN * 64, wsn4);
    cast_fcw48<<<(64 * 48 + 255) / 256, 256, 0, stream>>>(fcw, fcw48);

    // ---- bucketed CSR build ----
    zero_i32<<<1, 256, 0, stream>>>(bcnt, 256);
    bucket_hist<<<EB, 256, 0, stream>>>(dst, bcnt, e);
    bucket_scan<<<1, 256, 0, stream>>>(bcnt, bbase, bcursor, NB, e);
    bucket_scatter<<<EB, 256, 0, stream>>>(src, dst, bcursor, ebuf, e);
    bucket_fill<<<NB, 256, 0, stream>>>(bbase, ebuf, row_ptr, dis, col, n, e);

    // ---- layers ----
    int mblocks = ((n + 63) / 64 + 3) / 4;
    int gblocks = (n + 15) / 16;
    for (int l = 0; l < LL; l++) {
        if (l == 0)
            matmul_mfma<FIN><<<mblocks, 256, 0, stream>>>(x16, w16, dis, g16, n);
        else
            matmul_mfma<HH><<<mblocks, 256, 0, stream>>>(h16, w16 + FIN * 64 + (size_t)(l - 1) * 64 * 64,
                                                         dis, g16, n);

        gather_relu_jk<<<gblocks, 256, 0, stream>>>(row_ptr, col, dis, g16,
                                                    bs + (size_t)l * HH, h16, jk16, n, l);
    }

    int fblocks = ((n + 15) / 16 + 3) / 4;
    fc_logsoftmax_mfma<<<fblocks, 256, 0, stream>>>(jk16, fcw48, fcb, out, n);
}

// Round 6
// 393.573 us; speedup vs baseline: 7.1011x; 1.0625x over previous
//
#include <hip/hip_runtime.h>
#include <math.h>

#define FIN 128
#define HH 64
#define CC 40
#define LL 6
#define EPB 4096   // edges per block for hist/scatter

typedef __attribute__((ext_vector_type(8))) short bf16x8;
typedef __attribute__((ext_vector_type(4))) float f32x4;

__device__ __forceinline__ ushort f2b(float f) {
    union { float f; unsigned u; } c; c.f = f;
    unsigned u = c.u;
    return (ushort)((u + 0x7FFFu + ((u >> 16) & 1u)) >> 16);  // RNE
}
__device__ __forceinline__ float b2f(ushort h) {
    union { float f; unsigned u; } c; c.u = ((unsigned)h) << 16;
    return c.f;
}

// ---------------- casts ----------------

__global__ void cast_f32_bf16(const float* __restrict__ in, ushort* __restrict__ out, int n4) {
    int i = blockIdx.x * blockDim.x + threadIdx.x;
    if (i < n4) {
        float4 v = ((const float4*)in)[i];
        ushort4 o;
        o.x = f2b(v.x); o.y = f2b(v.y); o.z = f2b(v.z); o.w = f2b(v.w);
        ((ushort4*)out)[i] = o;
    }
}

// fcw [64][40] f32 -> [64][48] bf16 (pad cols 40..47 with 0)
__global__ void cast_fcw48(const float* __restrict__ fcw, ushort* __restrict__ out) {
    int i = blockIdx.x * blockDim.x + threadIdx.x;  // 64*48
    if (i < 64 * 48) {
        int k = i / 48, c = i % 48;
        out[i] = (c < CC) ? f2b(fcw[k * CC + c]) : (ushort)0;
    }
}

__global__ void zero_i32(int* p, int n) {
    int i = blockIdx.x * blockDim.x + threadIdx.x;
    if (i < n) p[i] = 0;
}

// ---------------- bucketed CSR build ----------------
// bucket b = dst >> 9 (512 nodes per bucket)

__global__ __launch_bounds__(256) void bucket_hist(const int* __restrict__ dst, int* bcnt, int e) {
    __shared__ int lh[256];
    int t = threadIdx.x;
    lh[t] = 0;
    __syncthreads();
    int base = blockIdx.x * EPB;
#pragma unroll
    for (int u = 0; u < 16; u++) {
        int i = base + t + u * 256;
        if (i < e) atomicAdd(&lh[dst[i] >> 9], 1);
    }
    __syncthreads();
    if (lh[t]) atomicAdd(&bcnt[t], lh[t]);
}

__global__ __launch_bounds__(256) void bucket_scan(const int* __restrict__ bcnt,
                                                   int* bbase, int* bcursor, int NB, int e) {
    __shared__ int s[256];
    int t = threadIdx.x;
    int v = (t < NB) ? bcnt[t] : 0;
    s[t] = v; __syncthreads();
    for (int off = 1; off < 256; off <<= 1) {
        int x = t >= off ? s[t - off] : 0;
        __syncthreads();
        s[t] += x;
        __syncthreads();
    }
    int excl = s[t] - v;
    if (t < NB) { bbase[t] = excl; bcursor[t] = excl; }
    if (t == 0) bbase[NB] = e;
}

// ebuf entry: (src << 9) | (dst & 511)
__global__ __launch_bounds__(256) void bucket_scatter(const int* __restrict__ src,
                                                      const int* __restrict__ dst,
                                                      int* bcursor, unsigned* __restrict__ ebuf, int e) {
    __shared__ int lh[256];
    __shared__ int lbase[256];
    int t = threadIdx.x;
    int base = blockIdx.x * EPB;
    lh[t] = 0;
    __syncthreads();

    int ls[16], ld[16];
#pragma unroll
    for (int u = 0; u < 16; u++) {
        int i = base + t + u * 256;
        if (i < e) { ls[u] = src[i]; ld[u] = dst[i]; }
        else       { ls[u] = 0;      ld[u] = -1; }
    }
#pragma unroll
    for (int u = 0; u < 16; u++)
        if (ld[u] >= 0) atomicAdd(&lh[ld[u] >> 9], 1);
    __syncthreads();

    int nb = lh[t];
    if (nb > 0) lbase[t] = atomicAdd(&bcursor[t], nb);
    lh[t] = 0;
    __syncthreads();

#pragma unroll
    for (int u = 0; u < 16; u++) {
        if (ld[u] >= 0) {
            int bq = ld[u] >> 9;
            int p = atomicAdd(&lh[bq], 1);
            ebuf[lbase[bq] + p] = ((unsigned)ls[u] << 9) | (unsigned)(ld[u] & 511);
        }
    }
}

__global__ __launch_bounds__(256) void bucket_fill(const int* __restrict__ bbase,
                                                   const unsigned* __restrict__ ebuf,
                                                   int* __restrict__ row_ptr,
                                                   float* __restrict__ dis,
                                                   int* __restrict__ col, int n, int e) {
    __shared__ int nc[512];
    __shared__ int cur[512];
    __shared__ int sp[256];
    int b = blockIdx.x, t = threadIdx.x;
    int node0 = b << 9;
    int estart = bbase[b], eend = bbase[b + 1];

    nc[t] = 0; nc[t + 256] = 0;
    __syncthreads();
    for (int i = estart + t; i < eend; i += 256)
        atomicAdd(&nc[ebuf[i] & 511u], 1);
    __syncthreads();

    int c0 = nc[2 * t], c1 = nc[2 * t + 1];
    int pair = c0 + c1;
    sp[t] = pair; __syncthreads();
    for (int off = 1; off < 256; off <<= 1) {
        int x = t >= off ? sp[t - off] : 0;
        __syncthreads();
        sp[t] += x;
        __syncthreads();
    }
    int excl = sp[t] - pair;
    cur[2 * t] = excl;
    cur[2 * t + 1] = excl + c0;

    int n0 = node0 + 2 * t, n1 = node0 + 2 * t + 1;
    if (n0 < n) { row_ptr[n0] = estart + excl;      dis[n0] = rsqrtf((float)c0 + 1.0f); }
    if (n1 < n) { row_ptr[n1] = estart + excl + c0; dis[n1] = rsqrtf((float)c1 + 1.0f); }
    if (b == 0 && t == 0) row_ptr[n] = e;
    __syncthreads();

    for (int i = estart + t; i < eend; i += 256) {
        unsigned v = ebuf[i];
        int p = atomicAdd(&cur[v & 511u], 1);
        col[estart + p] = (int)(v >> 9);
    }
}

// ---------------- MFMA matmul: g[n][64] = (in[n][K] @ W[K][64]) * dis[row], bf16 ----------------
// One 16-row tile per wave (occupancy-first; W frags are L1-hot).

template <int K>
__global__ __launch_bounds__(256) void matmul_mfma(const ushort* __restrict__ A,
                                                   const ushort* __restrict__ W,
                                                   const float* __restrict__ dis,
                                                   ushort* __restrict__ out, int n) {
    int wave = threadIdx.x >> 6;
    int lane = threadIdx.x & 63;
    int row0 = (blockIdx.x * 4 + wave) * 16;
    if (row0 >= n) return;

    int lm = lane & 15;
    int lg = lane >> 4;
    constexpr int KH = K / 32;

    int arow = row0 + lm;
    if (arow >= n) arow = n - 1;
    bf16x8 afrag[KH];
#pragma unroll
    for (int kh = 0; kh < KH; kh++)
        afrag[kh] = *(const bf16x8*)(A + (size_t)arow * K + kh * 32 + lg * 8);

    bf16x8 bfrag[4][KH];
#pragma unroll
    for (int c = 0; c < 4; c++) {
#pragma unroll
        for (int kh = 0; kh < KH; kh++) {
            int kbase = kh * 32 + lg * 8;
            int ncol = c * 16 + lm;
            bf16x8 bb;
#pragma unroll
            for (int e2 = 0; e2 < 8; e2++) bb[e2] = (short)W[(size_t)(kbase + e2) * 64 + ncol];
            bfrag[c][kh] = bb;
        }
    }

    f32x4 acc[4];
#pragma unroll
    for (int c = 0; c < 4; c++) acc[c] = (f32x4){0.f, 0.f, 0.f, 0.f};

#pragma unroll
    for (int c = 0; c < 4; c++)
#pragma unroll
        for (int kh = 0; kh < KH; kh++)
            acc[c] = __builtin_amdgcn_mfma_f32_16x16x32_bf16(afrag[kh], bfrag[c][kh], acc[c], 0, 0, 0);

    float dsr[4];
#pragma unroll
    for (int r = 0; r < 4; r++) {
        int row = row0 + lg * 4 + r;
        dsr[r] = (row < n) ? dis[row] : 0.0f;
    }
#pragma unroll
    for (int c = 0; c < 4; c++) {
#pragma unroll
        for (int r = 0; r < 4; r++) {
            int row = row0 + lg * 4 + r;
            if (row < n) out[(size_t)row * 64 + c * 16 + lm] = f2b(acc[c][r] * dsr[r]);
        }
    }
}

// ---------------- fused gather + bias + relu + JK-max ----------------
// g rows pre-scaled by dis[src]; agg = dsi * (sum g[cols] + g[i]).
// 4 nodes/wave (16 lanes each), lane = 4 feats (ushort4); edge loop unrolled 8.

__global__ __launch_bounds__(256) void gather_relu_jk(const int* __restrict__ row_ptr,
                                                      const int* __restrict__ col,
                                                      const float* __restrict__ dis,
                                                      const ushort* __restrict__ g,
                                                      const float* __restrict__ b,
                                                      ushort* __restrict__ h,
                                                      ushort* __restrict__ jk,
                                                      int n, int layer) {
    int wave = threadIdx.x >> 6;
    int lane = threadIdx.x & 63;
    int sub = lane >> 4;
    int fl = (lane & 15) * 4;
    int i = (blockIdx.x * 4 + wave) * 4 + sub;
    if (i >= n) return;

    float dsi = dis[i];
    ushort4 sv = *(const ushort4*)(g + (size_t)i * 64 + fl);
    float a0 = b2f(sv.x), a1 = b2f(sv.y), a2 = b2f(sv.z), a3 = b2f(sv.w);

    int k = row_ptr[i];
    int end = row_ptr[i + 1];

    for (; k + 7 < end; k += 8) {
        int s[8];
#pragma unroll
        for (int u = 0; u < 8; u++) s[u] = col[k + u];
        ushort4 v[8];
#pragma unroll
        for (int u = 0; u < 8; u++) v[u] = *(const ushort4*)(g + (size_t)s[u] * 64 + fl);
#pragma unroll
        for (int u = 0; u < 8; u++) {
            a0 += b2f(v[u].x); a1 += b2f(v[u].y);
            a2 += b2f(v[u].z); a3 += b2f(v[u].w);
        }
    }
    for (; k + 3 < end; k += 4) {
        int s0 = col[k], s1 = col[k + 1], s2 = col[k + 2], s3 = col[k + 3];
        ushort4 v0 = *(const ushort4*)(g + (size_t)s0 * 64 + fl);
        ushort4 v1 = *(const ushort4*)(g + (size_t)s1 * 64 + fl);
        ushort4 v2 = *(const ushort4*)(g + (size_t)s2 * 64 + fl);
        ushort4 v3 = *(const ushort4*)(g + (size_t)s3 * 64 + fl);
        a0 += (b2f(v0.x) + b2f(v1.x)) + (b2f(v2.x) + b2f(v3.x));
        a1 += (b2f(v0.y) + b2f(v1.y)) + (b2f(v2.y) + b2f(v3.y));
        a2 += (b2f(v0.z) + b2f(v1.z)) + (b2f(v2.z) + b2f(v3.z));
        a3 += (b2f(v0.w) + b2f(v1.w)) + (b2f(v2.w) + b2f(v3.w));
    }
    for (; k < end; k++) {
        int s0 = col[k];
        ushort4 v0 = *(const ushort4*)(g + (size_t)s0 * 64 + fl);
        a0 += b2f(v0.x); a1 += b2f(v0.y); a2 += b2f(v0.z); a3 += b2f(v0.w);
    }

    float4 bb = *(const float4*)(b + fl);
    ushort4 hv;
    hv.x = f2b(fmaxf(a0 * dsi + bb.x, 0.0f));
    hv.y = f2b(fmaxf(a1 * dsi + bb.y, 0.0f));
    hv.z = f2b(fmaxf(a2 * dsi + bb.z, 0.0f));
    hv.w = f2b(fmaxf(a3 * dsi + bb.w, 0.0f));

    size_t o = (size_t)i * 64 + fl;
    if (layer != LL - 1) *(ushort4*)(h + o) = hv;

    if (layer == 0) {
        *(ushort4*)(jk + o) = hv;
    } else {
        ushort4 jv = *(const ushort4*)(jk + o);
        jv.x = jv.x > hv.x ? jv.x : hv.x;
        jv.y = jv.y > hv.y ? jv.y : hv.y;
        jv.z = jv.z > hv.z ? jv.z : hv.z;
        jv.w = jv.w > hv.w ? jv.w : hv.w;
        *(ushort4*)(jk + o) = jv;
    }
}

// ---------------- MFMA FC + log_softmax ----------------

__global__ __launch_bounds__(256) void fc_logsoftmax_mfma(const ushort* __restrict__ jk,
                                                          const ushort* __restrict__ fcw48,
                                                          const float* __restrict__ fcb,
                                                          float* __restrict__ out, int n) {
    int wave = threadIdx.x >> 6;
    int lane = threadIdx.x & 63;
    int row0 = (blockIdx.x * 4 + wave) * 16;
    if (row0 >= n) return;

    int lm = lane & 15;
    int lg = lane >> 4;

    bf16x8 bfrag[3][2];
#pragma unroll
    for (int c = 0; c < 3; c++) {
#pragma unroll
        for (int kh = 0; kh < 2; kh++) {
            int kbase = kh * 32 + lg * 8;
            bf16x8 bb;
#pragma unroll
            for (int e2 = 0; e2 < 8; e2++) bb[e2] = (short)fcw48[(size_t)(kbase + e2) * 48 + c * 16 + lm];
            bfrag[c][kh] = bb;
        }
    }

    int arow = row0 + lm;
    if (arow >= n) arow = n - 1;
    bf16x8 afrag[2];
#pragma unroll
    for (int kh = 0; kh < 2; kh++)
        afrag[kh] = *(const bf16x8*)(jk + (size_t)arow * 64 + kh * 32 + lg * 8);

    f32x4 acc[3];
#pragma unroll
    for (int c = 0; c < 3; c++) acc[c] = (f32x4){0.f, 0.f, 0.f, 0.f};
#pragma unroll
    for (int c = 0; c < 3; c++)
#pragma unroll
        for (int kh = 0; kh < 2; kh++)
            acc[c] = __builtin_amdgcn_mfma_f32_16x16x32_bf16(afrag[kh], bfrag[c][kh], acc[c], 0, 0, 0);

    bool valid[3];
    float bc[3];
#pragma unroll
    for (int c = 0; c < 3; c++) {
        int colp = c * 16 + lm;
        valid[c] = colp < CC;
        bc[c] = valid[c] ? fcb[colp] : 0.0f;
    }

#pragma unroll
    for (int r = 0; r < 4; r++) {
        float l0 = acc[0][r] + bc[0];
        float l1 = acc[1][r] + bc[1];
        float l2 = valid[2] ? (acc[2][r] + bc[2]) : -INFINITY;

        float m = fmaxf(fmaxf(l0, l1), l2);
#pragma unroll
        for (int off = 8; off; off >>= 1) m = fmaxf(m, __shfl_xor(m, off));

        float s = __expf(l0 - m) + __expf(l1 - m) + (valid[2] ? __expf(l2 - m) : 0.0f);
#pragma unroll
        for (int off = 8; off; off >>= 1) s += __shfl_xor(s, off);

        float lse = m + __logf(s);
        int row = row0 + lg * 4 + r;
        if (row < n) {
            float* orow = out + (size_t)row * CC;
            orow[lm] = l0 - lse;
            orow[16 + lm] = l1 - lse;
            if (valid[2]) orow[32 + lm] = l2 - lse;
        }
    }
}

// ---------------- host ----------------

extern "C" void kernel_launch(void* const* d_in, const int* in_sizes, int n_in,
                              void* d_out, int out_size, void* d_ws, size_t ws_size,
                              hipStream_t stream) {
    const float* x   = (const float*)d_in[0];
    const int*   edg = (const int*)d_in[1];
    const float* W0  = (const float*)d_in[2];
    const float* Ws  = (const float*)d_in[3];
    const float* bs  = (const float*)d_in[4];
    const float* fcw = (const float*)d_in[5];
    const float* fcb = (const float*)d_in[6];
    float* out = (float*)d_out;

    int n = in_sizes[0] / FIN;  // 100000
    int e = in_sizes[1] / 2;    // 1600000
    const int* src = edg;
    const int* dst = edg + e;

    char* ws = (char*)d_ws;
    size_t off = 0;
    auto alloc = [&](size_t bytes) -> void* {
        void* p = ws + off;
        off = (off + bytes + 255) & ~(size_t)255;
        return p;
    };
    ushort*   x16     = (ushort*)alloc((size_t)n * FIN * 2);
    ushort*   w16     = (ushort*)alloc((size_t)(FIN * 64 + (LL - 1) * 64 * 64) * 2);
    ushort*   fcw48   = (ushort*)alloc((size_t)64 * 48 * 2);
    ushort*   h16     = (ushort*)alloc((size_t)n * 64 * 2);
    ushort*   g16     = (ushort*)alloc((size_t)n * 64 * 2);
    ushort*   jk16    = (ushort*)alloc((size_t)n * 64 * 2);
    float*    dis     = (float*)alloc((size_t)n * 4);
    int*      row_ptr = (int*)alloc((size_t)(n + 1) * 4);
    int*      col     = (int*)alloc((size_t)e * 4);
    unsigned* ebuf    = (unsigned*)alloc((size_t)e * 4);
    int*      bcnt    = (int*)alloc(256 * 4);
    int*      bbase   = (int*)alloc(257 * 4);
    int*      bcursor = (int*)alloc(256 * 4);

    int NB = (n + 511) >> 9;          // 196 buckets
    int EB = (e + EPB - 1) / EPB;     // 391 edge blocks

    // ---- casts ----
    int xn4 = n * FIN / 4;
    cast_f32_bf16<<<(xn4 + 255) / 256, 256, 0, stream>>>(x, x16, xn4);
    int w0n4 = FIN * 64 / 4;
    cast_f32_bf16<<<(w0n4 + 255) / 256, 256, 0, stream>>>(W0, w16, w0n4);
    int wsn4 = (LL - 1) * 64 * 64 / 4;
    cast_f32_bf16<<<(wsn4 + 255) / 256, 256, 0, stream>>>(Ws, w16 + FIN * 64, wsn4);
    cast_fcw48<<<(64 * 48 + 255) / 256, 256, 0, stream>>>(fcw, fcw48);

    // ---- bucketed CSR build ----
    zero_i32<<<1, 256, 0, stream>>>(bcnt, 256);
    bucket_hist<<<EB, 256, 0, stream>>>(dst, bcnt, e);
    bucket_scan<<<1, 256, 0, stream>>>(bcnt, bbase, bcursor, NB, e);
    bucket_scatter<<<EB, 256, 0, stream>>>(src, dst, bcursor, ebuf, e);
    bucket_fill<<<NB, 256, 0, stream>>>(bbase, ebuf, row_ptr, dis, col, n, e);

    // ---- layers ----
    int mblocks = ((n + 15) / 16 + 3) / 4;
    int gblocks = (n + 15) / 16;
    for (int l = 0; l < LL; l++) {
        if (l == 0)
            matmul_mfma<FIN><<<mblocks, 256, 0, stream>>>(x16, w16, dis, g16, n);
        else
            matmul_mfma<HH><<<mblocks, 256, 0, stream>>>(h16, w16 + FIN * 64 + (size_t)(l - 1) * 64 * 64,
                                                         dis, g16, n);

        gather_relu_jk<<<gblocks, 256, 0, stream>>>(row_ptr, col, dis, g16,
                                                    bs + (size_t)l * HH, h16, jk16, n, l);
    }

    int fblocks = ((n + 15) / 16 + 3) / 4;
    fc_logsoftmax_mfma<<<fblocks, 256, 0, stream>>>(jk16, fcw48, fcb, out, n);
}

// Round 7
// 354.737 us; speedup vs baseline: 7.8785x; 1.1095x over previous
//
#include <hip/hip_runtime.h>
#include <math.h>

#define FIN 128
#define HH 64
#define CC 40
#define LL 6
#define EPB 4096   // edges per block for hist/scatter

typedef __attribute__((ext_vector_type(8))) short bf16x8;
typedef __attribute__((ext_vector_type(4))) float f32x4;
typedef __attribute__((ext_vector_type(2))) float f32x2;

__device__ __forceinline__ ushort f2b(float f) {
    union { float f; unsigned u; } c; c.f = f;
    unsigned u = c.u;
    return (ushort)((u + 0x7FFFu + ((u >> 16) & 1u)) >> 16);  // RNE
}
__device__ __forceinline__ float b2f(ushort h) {
    union { float f; unsigned u; } c; c.u = ((unsigned)h) << 16;
    return c.f;
}
// single f32 -> fp8 e4m3 byte (OCP on gfx950)
__device__ __forceinline__ unsigned f2fp8(float v) {
    return (unsigned)__builtin_amdgcn_cvt_pk_fp8_f32(v, v, 0, false) & 0xFFu;
}

// ---------------- casts ----------------

__global__ void cast_f32_bf16(const float* __restrict__ in, ushort* __restrict__ out, int n4) {
    int i = blockIdx.x * blockDim.x + threadIdx.x;
    if (i < n4) {
        float4 v = ((const float4*)in)[i];
        ushort4 o;
        o.x = f2b(v.x); o.y = f2b(v.y); o.z = f2b(v.z); o.w = f2b(v.w);
        ((ushort4*)out)[i] = o;
    }
}

// fcw [64][40] f32 -> [64][48] bf16 (pad cols 40..47 with 0)
__global__ void cast_fcw48(const float* __restrict__ fcw, ushort* __restrict__ out) {
    int i = blockIdx.x * blockDim.x + threadIdx.x;  // 64*48
    if (i < 64 * 48) {
        int k = i / 48, c = i % 48;
        out[i] = (c < CC) ? f2b(fcw[k * CC + c]) : (ushort)0;
    }
}

__global__ void zero_i32(int* p, int n) {
    int i = blockIdx.x * blockDim.x + threadIdx.x;
    if (i < n) p[i] = 0;
}

// ---------------- bucketed CSR build ----------------
// bucket b = dst >> 9 (512 nodes per bucket)

__global__ __launch_bounds__(256) void bucket_hist(const int* __restrict__ dst, int* bcnt, int e) {
    __shared__ int lh[256];
    int t = threadIdx.x;
    lh[t] = 0;
    __syncthreads();
    int base = blockIdx.x * EPB;
#pragma unroll
    for (int u = 0; u < 16; u++) {
        int i = base + t + u * 256;
        if (i < e) atomicAdd(&lh[dst[i] >> 9], 1);
    }
    __syncthreads();
    if (lh[t]) atomicAdd(&bcnt[t], lh[t]);
}

__global__ __launch_bounds__(256) void bucket_scan(const int* __restrict__ bcnt,
                                                   int* bbase, int* bcursor, int NB, int e) {
    __shared__ int s[256];
    int t = threadIdx.x;
    int v = (t < NB) ? bcnt[t] : 0;
    s[t] = v; __syncthreads();
    for (int off = 1; off < 256; off <<= 1) {
        int x = t >= off ? s[t - off] : 0;
        __syncthreads();
        s[t] += x;
        __syncthreads();
    }
    int excl = s[t] - v;
    if (t < NB) { bbase[t] = excl; bcursor[t] = excl; }
    if (t == 0) bbase[NB] = e;
}

// ebuf entry: (src << 9) | (dst & 511)
__global__ __launch_bounds__(256) void bucket_scatter(const int* __restrict__ src,
                                                      const int* __restrict__ dst,
                                                      int* bcursor, unsigned* __restrict__ ebuf, int e) {
    __shared__ int lh[256];
    __shared__ int lbase[256];
    int t = threadIdx.x;
    int base = blockIdx.x * EPB;
    lh[t] = 0;
    __syncthreads();

    int ls[16], ld[16];
#pragma unroll
    for (int u = 0; u < 16; u++) {
        int i = base + t + u * 256;
        if (i < e) { ls[u] = src[i]; ld[u] = dst[i]; }
        else       { ls[u] = 0;      ld[u] = -1; }
    }
#pragma unroll
    for (int u = 0; u < 16; u++)
        if (ld[u] >= 0) atomicAdd(&lh[ld[u] >> 9], 1);
    __syncthreads();

    int nb = lh[t];
    if (nb > 0) lbase[t] = atomicAdd(&bcursor[t], nb);
    lh[t] = 0;
    __syncthreads();

#pragma unroll
    for (int u = 0; u < 16; u++) {
        if (ld[u] >= 0) {
            int bq = ld[u] >> 9;
            int p = atomicAdd(&lh[bq], 1);
            ebuf[lbase[bq] + p] = ((unsigned)ls[u] << 9) | (unsigned)(ld[u] & 511);
        }
    }
}

__global__ __launch_bounds__(256) void bucket_fill(const int* __restrict__ bbase,
                                                   const unsigned* __restrict__ ebuf,
                                                   int* __restrict__ row_ptr,
                                                   float* __restrict__ dis,
                                                   int* __restrict__ col, int n, int e) {
    __shared__ int nc[512];
    __shared__ int cur[512];
    __shared__ int sp[256];
    int b = blockIdx.x, t = threadIdx.x;
    int node0 = b << 9;
    int estart = bbase[b], eend = bbase[b + 1];

    nc[t] = 0; nc[t + 256] = 0;
    __syncthreads();
    for (int i = estart + t; i < eend; i += 256)
        atomicAdd(&nc[ebuf[i] & 511u], 1);
    __syncthreads();

    int c0 = nc[2 * t], c1 = nc[2 * t + 1];
    int pair = c0 + c1;
    sp[t] = pair; __syncthreads();
    for (int off = 1; off < 256; off <<= 1) {
        int x = t >= off ? sp[t - off] : 0;
        __syncthreads();
        sp[t] += x;
        __syncthreads();
    }
    int excl = sp[t] - pair;
    cur[2 * t] = excl;
    cur[2 * t + 1] = excl + c0;

    int n0 = node0 + 2 * t, n1 = node0 + 2 * t + 1;
    if (n0 < n) { row_ptr[n0] = estart + excl;      dis[n0] = rsqrtf((float)c0 + 1.0f); }
    if (n1 < n) { row_ptr[n1] = estart + excl + c0; dis[n1] = rsqrtf((float)c1 + 1.0f); }
    if (b == 0 && t == 0) row_ptr[n] = e;
    __syncthreads();

    for (int i = estart + t; i < eend; i += 256) {
        unsigned v = ebuf[i];
        int p = atomicAdd(&cur[v & 511u], 1);
        col[estart + p] = (int)(v >> 9);
    }
}

// ---------------- MFMA matmul: g8[n][64] = fp8((in[n][K] @ W[K][64]) * dis[row]) ----------------
// One 16-row tile per wave. F32IN: read f32 input, cast to bf16 in-register (layer 0).

template <int K, bool F32IN>
__global__ __launch_bounds__(256) void matmul_mfma(const void* __restrict__ Ain,
                                                   const ushort* __restrict__ W,
                                                   const float* __restrict__ dis,
                                                   unsigned char* __restrict__ out8, int n) {
    int wave = threadIdx.x >> 6;
    int lane = threadIdx.x & 63;
    int row0 = (blockIdx.x * 4 + wave) * 16;
    if (row0 >= n) return;

    int lm = lane & 15;
    int lg = lane >> 4;
    constexpr int KH = K / 32;

    int arow = row0 + lm;
    if (arow >= n) arow = n - 1;
    bf16x8 afrag[KH];
    if constexpr (F32IN) {
        const float* A32 = (const float*)Ain;
#pragma unroll
        for (int kh = 0; kh < KH; kh++) {
            const float* p = A32 + (size_t)arow * K + kh * 32 + lg * 8;
            float4 u0 = *(const float4*)(p);
            float4 u1 = *(const float4*)(p + 4);
            bf16x8 a;
            a[0] = (short)f2b(u0.x); a[1] = (short)f2b(u0.y);
            a[2] = (short)f2b(u0.z); a[3] = (short)f2b(u0.w);
            a[4] = (short)f2b(u1.x); a[5] = (short)f2b(u1.y);
            a[6] = (short)f2b(u1.z); a[7] = (short)f2b(u1.w);
            afrag[kh] = a;
        }
    } else {
        const ushort* A16 = (const ushort*)Ain;
#pragma unroll
        for (int kh = 0; kh < KH; kh++)
            afrag[kh] = *(const bf16x8*)(A16 + (size_t)arow * K + kh * 32 + lg * 8);
    }

    bf16x8 bfrag[4][KH];
#pragma unroll
    for (int c = 0; c < 4; c++) {
#pragma unroll
        for (int kh = 0; kh < KH; kh++) {
            int kbase = kh * 32 + lg * 8;
            int ncol = c * 16 + lm;
            bf16x8 bb;
#pragma unroll
            for (int e2 = 0; e2 < 8; e2++) bb[e2] = (short)W[(size_t)(kbase + e2) * 64 + ncol];
            bfrag[c][kh] = bb;
        }
    }

    f32x4 acc[4];
#pragma unroll
    for (int c = 0; c < 4; c++) acc[c] = (f32x4){0.f, 0.f, 0.f, 0.f};

#pragma unroll
    for (int c = 0; c < 4; c++)
#pragma unroll
        for (int kh = 0; kh < KH; kh++)
            acc[c] = __builtin_amdgcn_mfma_f32_16x16x32_bf16(afrag[kh], bfrag[c][kh], acc[c], 0, 0, 0);

    float dsr[4];
#pragma unroll
    for (int r = 0; r < 4; r++) {
        int row = row0 + lg * 4 + r;
        dsr[r] = (row < n) ? dis[row] : 0.0f;
    }
#pragma unroll
    for (int c = 0; c < 4; c++) {
#pragma unroll
        for (int r = 0; r < 4; r++) {
            int row = row0 + lg * 4 + r;
            if (row < n) out8[(size_t)row * 64 + c * 16 + lm] = (unsigned char)f2fp8(acc[c][r] * dsr[r]);
        }
    }
}

// ---------------- fused gather + bias + relu + JK-max ----------------
// g8 rows (fp8 e4m3) pre-scaled by dis[src]; agg = dsi * (sum g[cols] + g[i]).
// 4 nodes/wave (16 lanes each), lane = 4 feats (4 bytes); edge loop unrolled 16.

__global__ __launch_bounds__(256) void gather_relu_jk(const int* __restrict__ row_ptr,
                                                      const int* __restrict__ col,
                                                      const float* __restrict__ dis,
                                                      const unsigned char* __restrict__ g8,
                                                      const float* __restrict__ b,
                                                      ushort* __restrict__ h,
                                                      ushort* __restrict__ jk,
                                                      int n, int layer) {
    int wave = threadIdx.x >> 6;
    int lane = threadIdx.x & 63;
    int sub = lane >> 4;
    int fl = (lane & 15) * 4;   // feature offset (== byte offset in fp8 row)
    int i = (blockIdx.x * 4 + wave) * 4 + sub;
    if (i >= n) return;

    float dsi = dis[i];
    float a0 = 0.f, a1 = 0.f, a2 = 0.f, a3 = 0.f;
    {
        unsigned w = *(const unsigned*)(g8 + (size_t)i * 64 + fl);
        f32x2 lo = __builtin_amdgcn_cvt_pk_f32_fp8(w, false);
        f32x2 hi = __builtin_amdgcn_cvt_pk_f32_fp8(w, true);
        a0 = lo[0]; a1 = lo[1]; a2 = hi[0]; a3 = hi[1];
    }

    int k = row_ptr[i];
    int end = row_ptr[i + 1];

    for (; k + 15 < end; k += 16) {
        int s[16];
#pragma unroll
        for (int u = 0; u < 16; u++) s[u] = col[k + u];
        unsigned v[16];
#pragma unroll
        for (int u = 0; u < 16; u++) v[u] = *(const unsigned*)(g8 + (size_t)s[u] * 64 + fl);
#pragma unroll
        for (int u = 0; u < 16; u++) {
            f32x2 lo = __builtin_amdgcn_cvt_pk_f32_fp8(v[u], false);
            f32x2 hi = __builtin_amdgcn_cvt_pk_f32_fp8(v[u], true);
            a0 += lo[0]; a1 += lo[1]; a2 += hi[0]; a3 += hi[1];
        }
    }
    for (; k + 3 < end; k += 4) {
        int s[4];
#pragma unroll
        for (int u = 0; u < 4; u++) s[u] = col[k + u];
        unsigned v[4];
#pragma unroll
        for (int u = 0; u < 4; u++) v[u] = *(const unsigned*)(g8 + (size_t)s[u] * 64 + fl);
#pragma unroll
        for (int u = 0; u < 4; u++) {
            f32x2 lo = __builtin_amdgcn_cvt_pk_f32_fp8(v[u], false);
            f32x2 hi = __builtin_amdgcn_cvt_pk_f32_fp8(v[u], true);
            a0 += lo[0]; a1 += lo[1]; a2 += hi[0]; a3 += hi[1];
        }
    }
    for (; k < end; k++) {
        unsigned w = *(const unsigned*)(g8 + (size_t)col[k] * 64 + fl);
        f32x2 lo = __builtin_amdgcn_cvt_pk_f32_fp8(w, false);
        f32x2 hi = __builtin_amdgcn_cvt_pk_f32_fp8(w, true);
        a0 += lo[0]; a1 += lo[1]; a2 += hi[0]; a3 += hi[1];
    }

    float4 bb = *(const float4*)(b + fl);
    ushort4 hv;
    hv.x = f2b(fmaxf(a0 * dsi + bb.x, 0.0f));
    hv.y = f2b(fmaxf(a1 * dsi + bb.y, 0.0f));
    hv.z = f2b(fmaxf(a2 * dsi + bb.z, 0.0f));
    hv.w = f2b(fmaxf(a3 * dsi + bb.w, 0.0f));

    size_t o = (size_t)i * 64 + fl;
    if (layer != LL - 1) *(ushort4*)(h + o) = hv;

    if (layer == 0) {
        *(ushort4*)(jk + o) = hv;
    } else {
        ushort4 jv = *(const ushort4*)(jk + o);
        jv.x = jv.x > hv.x ? jv.x : hv.x;
        jv.y = jv.y > hv.y ? jv.y : hv.y;
        jv.z = jv.z > hv.z ? jv.z : hv.z;
        jv.w = jv.w > hv.w ? jv.w : hv.w;
        *(ushort4*)(jk + o) = jv;
    }
}

// ---------------- MFMA FC + log_softmax ----------------

__global__ __launch_bounds__(256) void fc_logsoftmax_mfma(const ushort* __restrict__ jk,
                                                          const ushort* __restrict__ fcw48,
                                                          const float* __restrict__ fcb,
                                                          float* __restrict__ out, int n) {
    int wave = threadIdx.x >> 6;
    int lane = threadIdx.x & 63;
    int row0 = (blockIdx.x * 4 + wave) * 16;
    if (row0 >= n) return;

    int lm = lane & 15;
    int lg = lane >> 4;

    bf16x8 bfrag[3][2];
#pragma unroll
    for (int c = 0; c < 3; c++) {
#pragma unroll
        for (int kh = 0; kh < 2; kh++) {
            int kbase = kh * 32 + lg * 8;
            bf16x8 bb;
#pragma unroll
            for (int e2 = 0; e2 < 8; e2++) bb[e2] = (short)fcw48[(size_t)(kbase + e2) * 48 + c * 16 + lm];
            bfrag[c][kh] = bb;
        }
    }

    int arow = row0 + lm;
    if (arow >= n) arow = n - 1;
    bf16x8 afrag[2];
#pragma unroll
    for (int kh = 0; kh < 2; kh++)
        afrag[kh] = *(const bf16x8*)(jk + (size_t)arow * 64 + kh * 32 + lg * 8);

    f32x4 acc[3];
#pragma unroll
    for (int c = 0; c < 3; c++) acc[c] = (f32x4){0.f, 0.f, 0.f, 0.f};
#pragma unroll
    for (int c = 0; c < 3; c++)
#pragma unroll
        for (int kh = 0; kh < 2; kh++)
            acc[c] = __builtin_amdgcn_mfma_f32_16x16x32_bf16(afrag[kh], bfrag[c][kh], acc[c], 0, 0, 0);

    bool valid[3];
    float bc[3];
#pragma unroll
    for (int c = 0; c < 3; c++) {
        int colp = c * 16 + lm;
        valid[c] = colp < CC;
        bc[c] = valid[c] ? fcb[colp] : 0.0f;
    }

#pragma unroll
    for (int r = 0; r < 4; r++) {
        float l0 = acc[0][r] + bc[0];
        float l1 = acc[1][r] + bc[1];
        float l2 = valid[2] ? (acc[2][r] + bc[2]) : -INFINITY;

        float m = fmaxf(fmaxf(l0, l1), l2);
#pragma unroll
        for (int off = 8; off; off >>= 1) m = fmaxf(m, __shfl_xor(m, off));

        float s = __expf(l0 - m) + __expf(l1 - m) + (valid[2] ? __expf(l2 - m) : 0.0f);
#pragma unroll
        for (int off = 8; off; off >>= 1) s += __shfl_xor(s, off);

        float lse = m + __logf(s);
        int row = row0 + lg * 4 + r;
        if (row < n) {
            float* orow = out + (size_t)row * CC;
            orow[lm] = l0 - lse;
            orow[16 + lm] = l1 - lse;
            if (valid[2]) orow[32 + lm] = l2 - lse;
        }
    }
}

// ---------------- host ----------------

extern "C" void kernel_launch(void* const* d_in, const int* in_sizes, int n_in,
                              void* d_out, int out_size, void* d_ws, size_t ws_size,
                              hipStream_t stream) {
    const float* x   = (const float*)d_in[0];
    const int*   edg = (const int*)d_in[1];
    const float* W0  = (const float*)d_in[2];
    const float* Ws  = (const float*)d_in[3];
    const float* bs  = (const float*)d_in[4];
    const float* fcw = (const float*)d_in[5];
    const float* fcb = (const float*)d_in[6];
    float* out = (float*)d_out;

    int n = in_sizes[0] / FIN;  // 100000
    int e = in_sizes[1] / 2;    // 1600000
    const int* src = edg;
    const int* dst = edg + e;

    char* ws = (char*)d_ws;
    size_t off = 0;
    auto alloc = [&](size_t bytes) -> void* {
        void* p = ws + off;
        off = (off + bytes + 255) & ~(size_t)255;
        return p;
    };
    ushort*        w16     = (ushort*)alloc((size_t)(FIN * 64 + (LL - 1) * 64 * 64) * 2);
    ushort*        fcw48   = (ushort*)alloc((size_t)64 * 48 * 2);
    ushort*        h16     = (ushort*)alloc((size_t)n * 64 * 2);
    unsigned char* g8      = (unsigned char*)alloc((size_t)n * 64);
    ushort*        jk16    = (ushort*)alloc((size_t)n * 64 * 2);
    float*         dis     = (float*)alloc((size_t)n * 4);
    int*           row_ptr = (int*)alloc((size_t)(n + 1) * 4);
    int*           col     = (int*)alloc((size_t)e * 4);
    unsigned*      ebuf    = (unsigned*)alloc((size_t)e * 4);
    int*           bcnt    = (int*)alloc(256 * 4);
    int*           bbase   = (int*)alloc(257 * 4);
    int*           bcursor = (int*)alloc(256 * 4);

    int NB = (n + 511) >> 9;          // 196 buckets
    int EB = (e + EPB - 1) / EPB;     // 391 edge blocks

    // ---- weight casts (tiny) ----
    int w0n4 = FIN * 64 / 4;
    cast_f32_bf16<<<(w0n4 + 255) / 256, 256, 0, stream>>>(W0, w16, w0n4);
    int wsn4 = (LL - 1) * 64 * 64 / 4;
    cast_f32_bf16<<<(wsn4 + 255) / 256, 256, 0, stream>>>(Ws, w16 + FIN * 64, wsn4);
    cast_fcw48<<<(64 * 48 + 255) / 256, 256, 0, stream>>>(fcw, fcw48);

    // ---- bucketed CSR build ----
    zero_i32<<<1, 256, 0, stream>>>(bcnt, 256);
    bucket_hist<<<EB, 256, 0, stream>>>(dst, bcnt, e);
    bucket_scan<<<1, 256, 0, stream>>>(bcnt, bbase, bcursor, NB, e);
    bucket_scatter<<<EB, 256, 0, stream>>>(src, dst, bcursor, ebuf, e);
    bucket_fill<<<NB, 256, 0, stream>>>(bbase, ebuf, row_ptr, dis, col, n, e);

    // ---- layers ----
    int mblocks = ((n + 15) / 16 + 3) / 4;
    int gblocks = (n + 15) / 16;
    for (int l = 0; l < LL; l++) {
        if (l == 0)
            matmul_mfma<FIN, true><<<mblocks, 256, 0, stream>>>(x, w16, dis, g8, n);
        else
            matmul_mfma<HH, false><<<mblocks, 256, 0, stream>>>(h16, w16 + FIN * 64 + (size_t)(l - 1) * 64 * 64,
                                                                dis, g8, n);

        gather_relu_jk<<<gblocks, 256, 0, stream>>>(row_ptr, col, dis, g8,
                                                    bs + (size_t)l * HH, h16, jk16, n, l);
    }

    int fblocks = ((n + 15) / 16 + 3) / 4;
    fc_logsoftmax_mfma<<<fblocks, 256, 0, stream>>>(jk16, fcw48, fcb, out, n);
}